// Round 11
// baseline (955.209 us; speedup 1.0000x reference)
//
#include <hip/hip_runtime.h>
#include <hip/hip_bf16.h>
#include <cstdint>
#include <cstddef>
#include <cmath>

#define B_     8192
#define XD_    4096
#define ZD_    1024
#define XE_    64
#define H_     128
#define ZN_    (B_*ZD_)

typedef __attribute__((ext_vector_type(8))) short short8_t;   // 8 x bf16 (4 VGPR)
typedef __attribute__((ext_vector_type(4))) float f32x4_t;    // MFMA accumulator
#define MFMA16(a,b,c) __builtin_amdgcn_mfma_f32_16x16x32_bf16((a),(b),(c),0,0,0)

// ---------------- threefry2x32 (bit-exact vs JAX, partitionable mode — validated R1-R10) ----
__host__ __device__ __forceinline__ uint32_t rotl32_(uint32_t x, int r){
#ifdef __HIP_DEVICE_COMPILE__
  return __builtin_rotateleft32(x, (uint32_t)r);
#else
  return (x<<r)|(x>>(32-r));
#endif
}

__host__ __device__ __forceinline__ void tf2x32(uint32_t k0, uint32_t k1,
                                                uint32_t x0, uint32_t x1,
                                                uint32_t* o0, uint32_t* o1){
  uint32_t k2 = k0 ^ k1 ^ 0x1BD11BDAu;
  x0 += k0; x1 += k1;
  x0 += x1; x1 = rotl32_(x1,13); x1 ^= x0;
  x0 += x1; x1 = rotl32_(x1,15); x1 ^= x0;
  x0 += x1; x1 = rotl32_(x1,26); x1 ^= x0;
  x0 += x1; x1 = rotl32_(x1, 6); x1 ^= x0;
  x0 += k1; x1 += k2 + 1u;
  x0 += x1; x1 = rotl32_(x1,17); x1 ^= x0;
  x0 += x1; x1 = rotl32_(x1,29); x1 ^= x0;
  x0 += x1; x1 = rotl32_(x1,16); x1 ^= x0;
  x0 += x1; x1 = rotl32_(x1,24); x1 ^= x0;
  x0 += k2; x1 += k0 + 2u;
  x0 += x1; x1 = rotl32_(x1,13); x1 ^= x0;
  x0 += x1; x1 = rotl32_(x1,15); x1 ^= x0;
  x0 += x1; x1 = rotl32_(x1,26); x1 ^= x0;
  x0 += x1; x1 = rotl32_(x1, 6); x1 ^= x0;
  x0 += k0; x1 += k1 + 3u;
  x0 += x1; x1 = rotl32_(x1,17); x1 ^= x0;
  x0 += x1; x1 = rotl32_(x1,29); x1 ^= x0;
  x0 += x1; x1 = rotl32_(x1,16); x1 ^= x0;
  x0 += x1; x1 = rotl32_(x1,24); x1 ^= x0;
  x0 += k1; x1 += k2 + 4u;
  x0 += x1; x1 = rotl32_(x1,13); x1 ^= x0;
  x0 += x1; x1 = rotl32_(x1,15); x1 ^= x0;
  x0 += x1; x1 = rotl32_(x1,26); x1 ^= x0;
  x0 += x1; x1 = rotl32_(x1, 6); x1 ^= x0;
  x0 += k2; x1 += k0 + 5u;
  *o0 = x0; *o1 = x1;
}

// XLA ErfInv32; fast v_log (validated R8-R10, absmax unchanged)
__device__ __forceinline__ float erfinv_(float x){
  float w = -__logf(fmaf(-x, x, 1.0f));
  float p;
  if (w < 5.0f){
    w -= 2.5f;
    p = 2.81022636e-08f;
    p = fmaf(p, w, 3.43273939e-07f);
    p = fmaf(p, w, -3.5233877e-06f);
    p = fmaf(p, w, -4.39150654e-06f);
    p = fmaf(p, w, 0.00021858087f);
    p = fmaf(p, w, -0.00125372503f);
    p = fmaf(p, w, -0.00417768164f);
    p = fmaf(p, w, 0.246640727f);
    p = fmaf(p, w, 1.50140941f);
  } else {
    w = sqrtf(w) - 3.0f;
    p = -0.000200214257f;
    p = fmaf(p, w, 0.000100950558f);
    p = fmaf(p, w, 0.00134934322f);
    p = fmaf(p, w, -0.00367342844f);
    p = fmaf(p, w, 0.00573950773f);
    p = fmaf(p, w, -0.0076224613f);
    p = fmaf(p, w, 0.00943887047f);
    p = fmaf(p, w, 1.00167406f);
    p = fmaf(p, w, 2.83297682f);
  }
  return p * x;
}

__device__ __forceinline__ float bits_to_normal(uint32_t bits){
  float f = __uint_as_float((bits >> 9) | 0x3f800000u) - 1.0f;
  float u = fmaxf(-0.99999994f, fmaf(f, 2.0f, -0.99999994f));
  return 1.41421356f * erfinv_(u);
}

__device__ __forceinline__ float rng_normal(uint32_t k0, uint32_t k1, uint32_t idx){
  uint32_t o0, o1; tf2x32(k0, k1, 0u, idx, &o0, &o1);
  return bits_to_normal(o0 ^ o1);
}

__device__ __forceinline__ ushort f2bf(float f){
  return __builtin_bit_cast(ushort, __float2bfloat16(f));
}
__device__ __forceinline__ float bf2f(ushort u){ return __uint_as_float(((uint32_t)u) << 16); }

// 8 bf16 normals (counters base..base+7) into a uint4 (registers)
__device__ __forceinline__ void gen8(uint32_t k0, uint32_t k1, uint32_t base, uint4* g){
  union { ushort u[8]; uint4 q; } pk;
  #pragma unroll
  for (int j = 0; j < 8; ++j) pk.u[j] = f2bf(rng_normal(k0,k1,base+(uint32_t)j));
  *g = pk.q;
}

// ---------------- weight-prep kernels (f32) ----------------
__global__ void k_prepA(const float* __restrict__ saWo, const float* __restrict__ saWqkv,
                        const float* __restrict__ caWo, const float* __restrict__ caWqkv,
                        float* __restrict__ S, float* __restrict__ U){
  int blk = blockIdx.x, tid = threadIdx.x;
  int idx = (blk & 255) * 64 + tid;
  int i = idx >> 7, j = idx & 127;
  if (blk < 256){
    float acc = (i == j) ? 1.0f : 0.0f;
    for (int k = 0; k < H_; ++k) acc += saWo[i*H_ + k] * saWqkv[(2*H_ + k)*H_ + j];
    S[idx] = acc;
  } else {
    float acc = 0.0f;
    for (int k = 0; k < H_; ++k) acc += caWo[i*H_ + k] * caWqkv[(2*H_ + k)*H_ + j];
    U[idx] = acc;
  }
}

__global__ void k_prepB(const float* __restrict__ saWo, const float* __restrict__ sabqkv, const float* __restrict__ sabo,
                        const float* __restrict__ caWo, const float* __restrict__ cabqkv, const float* __restrict__ cabo,
                        const float* __restrict__ W2, const float* __restrict__ pb2,
                        float* __restrict__ s0, float* __restrict__ u0, float* __restrict__ cb,
                        uint32_t* __restrict__ dkeys){
  int blk = blockIdx.x, tid = threadIdx.x;
  if (blk == 0 && tid == 0){
    for (uint32_t i = 0; i < 11; ++i){
      uint32_t a, b; tf2x32(0u, 42u, 0u, i, &a, &b);
      dkeys[2*i] = a; dkeys[2*i+1] = b;
    }
  }
  if (blk < 2){
    int i = blk*64 + tid;
    float acc = sabo[i];
    for (int k = 0; k < H_; ++k) acc += saWo[i*H_ + k] * sabqkv[2*H_ + k];
    s0[i] = acc;
  } else if (blk < 4){
    int i = (blk-2)*64 + tid;
    float acc = cabo[i];
    for (int k = 0; k < H_; ++k) acc += caWo[i*H_ + k] * cabqkv[2*H_ + k];
    u0[i] = acc;
  } else {
    int j = (blk-4)*64 + tid;
    float acc = 0.0f;
    for (int c = 0; c < XD_; ++c) acc += pb2[c] * W2[(size_t)c*H_ + j];
    cb[j] = acc;
  }
}

__global__ void k_prepM(const float* __restrict__ W2, float* __restrict__ M){
  int idx = blockIdx.x*64 + threadIdx.x;  // 16384
  int j1 = idx >> 7, j2 = idx & 127;
  float acc = 0.0f;
  for (int c = 0; c < XD_; ++c) acc += W2[(size_t)c*H_ + j1] * W2[(size_t)c*H_ + j2];
  M[idx] = acc;
}

__global__ void k_prepTR(const float* __restrict__ S, const float* __restrict__ U,
                         const float* __restrict__ xpW, const float* __restrict__ zpW,
                         const float* __restrict__ xpb, const float* __restrict__ zpb,
                         const float* __restrict__ s0, const float* __restrict__ u0,
                         float* __restrict__ T, float* __restrict__ R,
                         float* __restrict__ t0, float* __restrict__ r0v){
  int blk = blockIdx.x, tid = threadIdx.x;
  if (blk < 128){
    int idx = blk*64 + tid;
    int i = idx >> 6, e = idx & 63;
    float acc = 0.0f;
    for (int m = 0; m < H_; ++m) acc += S[i*H_ + m] * xpW[m*XE_ + e];
    T[idx] = acc;
  } else if (blk < 2176){
    int idx = (blk-128)*64 + tid;
    int i = idx >> 10, k = idx & 1023;
    float acc = 0.0f;
    for (int m = 0; m < H_; ++m) acc += U[i*H_ + m] * zpW[(size_t)m*ZD_ + k];
    R[idx] = acc;
  } else if (blk < 2178){
    int i = (blk-2176)*64 + tid;
    float acc = s0[i];
    for (int m = 0; m < H_; ++m) acc += S[i*H_ + m] * xpb[m];
    t0[i] = acc;
  } else {
    int i = (blk-2178)*64 + tid;
    float acc = u0[i];
    for (int m = 0; m < H_; ++m) acc += U[i*H_ + m] * zpb[m];
    r0v[i] = acc;
  }
}

__global__ void k_prepWXT(const float* __restrict__ W2, const float* __restrict__ T,
                          const float* __restrict__ embW, const float* __restrict__ embb,
                          const float* __restrict__ t0,
                          ushort* __restrict__ WXT, float* __restrict__ q0){
  int idx = blockIdx.x*256 + threadIdx.x;   // 1048576
  int j = idx >> 12, c = idx & 4095;
  float v;
  if (j < H_) v = W2[(size_t)c*H_ + j];
  else {
    int i = j - H_;
    float acc = 0.0f;
    for (int e = 0; e < XE_; ++e) acc += T[i*XE_ + e] * embW[(size_t)e*XD_ + c];
    v = acc;
  }
  WXT[idx] = f2bf(v);
  if (idx < H_){
    float acc = t0[idx];
    for (int e = 0; e < XE_; ++e) acc += T[idx*XE_ + e] * embb[e];
    q0[idx] = acc;
  }
}

// W2bf[524288], Mbf = 2*M [16384], FBT = [W1;R] [262144]
__global__ void k_conv(const float* __restrict__ W2, const float* __restrict__ W1,
                       const float* __restrict__ Mm, const float* __restrict__ R,
                       ushort* __restrict__ W2bf, ushort* __restrict__ Mbf,
                       ushort* __restrict__ FBT){
  int idx = blockIdx.x*256 + threadIdx.x;   // 802816
  if (idx < 524288) W2bf[idx] = f2bf(W2[idx]);
  else if (idx < 540672){ int i = idx - 524288; Mbf[i] = f2bf(2.0f*Mm[i]); }
  else { int i = idx - 540672; int j = i >> 10, k = i & 1023;
    FBT[i] = f2bf(j < H_ ? W1[j*ZD_ + k] : R[(size_t)(j-H_)*ZD_ + k]); }
}

// GGr [256][128] bf16: rows 0-127: -0.005*W1W1^T; rows 128-255: -0.005*dot(W1[k],R[j])
__global__ void k_prepG(const float* __restrict__ W1, const float* __restrict__ R,
                        ushort* __restrict__ GGr){
  int idx = blockIdx.x*64 + threadIdx.x;   // 32768
  int i = idx >> 7, k = idx & 127;
  float acc = 0.0f;
  if (i < 128){
    for (int m = 0; m < ZD_; ++m) acc += W1[(size_t)i*ZD_ + m] * W1[(size_t)k*ZD_ + m];
  } else {
    for (int m = 0; m < ZD_; ++m) acc += W1[(size_t)k*ZD_ + m] * R[(size_t)(i-128)*ZD_ + m];
  }
  GGr[idx] = f2bf(-0.005f * acc);
}

// ---------------- noise projection: pass p rows [8192][1024] RNG @ FBT^T -> [8192][256]
// R10 post-mortem: acc[16]=64 AGPR + 92 VGPR = 156 unified regs -> 8 waves/CU (2/SIMD)
// -> VALU 49-63% (stalls uncovered). Rebuilt: 512 thr (8 waves = 4 row-tiles x 2 col
// halves), acc[8]=32 AGPR -> ~115 regs -> 16 waves/CU (4/SIMD). RNG generated ONCE per
// block (col-halves share A via LDS). Double-buffered A, 1 barrier/iter; gen8-to-regs
// overlaps MFMA + L2 B-loads.
__global__ __launch_bounds__(512) void k_noiseproj(
    const ushort* __restrict__ FBT, const uint32_t* __restrict__ dkeys,
    float* __restrict__ y0c0, ushort* __restrict__ NWR){
  __shared__ __align__(16) ushort at[2][64*72];
  const int t = threadIdx.x, lane = t & 63, w = t >> 6;
  const int l15 = lane & 15, kq8 = (lane >> 4)*8, rq = (lane >> 4)*4;
  const int p = blockIdx.x >> 7, mb = blockIdx.x & 127;
  const int gb0 = mb*64;
  const uint32_t k0 = dkeys[2*p], k1 = dkeys[2*p+1];
  const int wr = w & 3, wc = w >> 2;
  const int arow = t >> 3, ak0 = (t & 7)*8;
  const uint32_t rbase = (uint32_t)(gb0 + arow)*1024u + (uint32_t)ak0;
  f32x4_t acc[8] = {};
  uint4 g;
  gen8(k0, k1, rbase, &g);
  *(uint4*)&at[0][arow*72 + ak0] = g;
  __syncthreads();
  #pragma unroll 1
  for (int it = 0; it < 16; ++it){
    if (it < 15) gen8(k0, k1, rbase + (uint32_t)((it+1)*64), &g);
    const ushort* ab = at[it&1] + (wr*16 + l15)*72;
    #pragma unroll
    for (int h = 0; h < 2; ++h){
      short8_t a = *(const short8_t*)(ab + h*32 + kq8);
      #pragma unroll
      for (int cf = 0; cf < 8; ++cf){
        short8_t b = *(const short8_t*)&FBT[(size_t)(wc*128 + cf*16 + l15)*ZD_ + it*64 + h*32 + kq8];
        acc[cf] = MFMA16(a, b, acc[cf]);
      }
    }
    if (it < 15) *(uint4*)&at[(it+1)&1][arow*72 + ak0] = g;
    __syncthreads();
  }
  #pragma unroll
  for (int cf = 0; cf < 8; ++cf){
    int col = wc*128 + cf*16 + l15;
    #pragma unroll
    for (int r = 0; r < 4; ++r){
      int row = gb0 + wr*16 + rq + r;
      float v = acc[cf][r];
      if (p == 0) y0c0[(size_t)row*256 + col] = v;
      else NWR[(size_t)(p-1)*2097152 + (size_t)row*256 + col] = f2bf(0.1f*v);
    }
  }
}

// ---------------- x-pass (MFMA, dbuf, 1 barrier/iter): [cneg | h1pre] = x @ WXT^T ----
// BM=32, BN=128, grid 512, 256 thr. Carried-register prefetch (R8-proven).
__global__ __launch_bounds__(256) void k_xpass_mfma(
    const float* __restrict__ x, const ushort* __restrict__ WXT,
    const float* __restrict__ cb, const float* __restrict__ q0,
    float* __restrict__ cneg, float* __restrict__ h1pre){
  __shared__ __align__(16) ushort xt[2][32*72];
  __shared__ __align__(16) ushort bt[2][128*72];
  const int t = threadIdx.x, lane = t & 63, w = t >> 6;
  const int bm = blockIdx.x >> 1, bn = blockIdx.x & 1;
  const int row0 = bm*32, ncol0 = bn*128;
  const int l15 = lane & 15, kq8 = (lane >> 4)*8, rq = (lane >> 4)*4;
  const int rt = w & 1, cb4 = (w >> 1)*4;
  const int xr = t >> 3, xk = (t & 7)*8;
  const int wn = t >> 1, wk = (t & 1)*32;
  f32x4_t acc[4] = {};
  {
    float4 v0 = *(const float4*)&x[(size_t)(row0+xr)*XD_ + xk];
    float4 v1 = *(const float4*)&x[(size_t)(row0+xr)*XD_ + xk + 4];
    union { ushort u[8]; uint4 q; } p;
    p.u[0]=f2bf(v0.x); p.u[1]=f2bf(v0.y); p.u[2]=f2bf(v0.z); p.u[3]=f2bf(v0.w);
    p.u[4]=f2bf(v1.x); p.u[5]=f2bf(v1.y); p.u[6]=f2bf(v1.z); p.u[7]=f2bf(v1.w);
    *(uint4*)&xt[0][xr*72 + xk] = p.q;
    const ushort* s = &WXT[(size_t)(ncol0+wn)*XD_ + wk];
    uint4 b0v=*(const uint4*)s, b1v=*(const uint4*)(s+8), b2v=*(const uint4*)(s+16), b3v=*(const uint4*)(s+24);
    ushort* d = &bt[0][wn*72 + wk];
    *(uint4*)d=b0v; *(uint4*)(d+8)=b1v; *(uint4*)(d+16)=b2v; *(uint4*)(d+24)=b3v;
  }
  float4 xv0, xv1; uint4 wb0, wb1, wb2, wb3;
  {
    xv0 = *(const float4*)&x[(size_t)(row0+xr)*XD_ + 64 + xk];
    xv1 = *(const float4*)&x[(size_t)(row0+xr)*XD_ + 64 + xk + 4];
    const ushort* s = &WXT[(size_t)(ncol0+wn)*XD_ + 64 + wk];
    wb0=*(const uint4*)s; wb1=*(const uint4*)(s+8); wb2=*(const uint4*)(s+16); wb3=*(const uint4*)(s+24);
  }
  #pragma unroll 1
  for (int it = 0; it < 64; ++it){
    __syncthreads();
    if (it < 63){
      union { ushort u[8]; uint4 q; } p;
      p.u[0]=f2bf(xv0.x); p.u[1]=f2bf(xv0.y); p.u[2]=f2bf(xv0.z); p.u[3]=f2bf(xv0.w);
      p.u[4]=f2bf(xv1.x); p.u[5]=f2bf(xv1.y); p.u[6]=f2bf(xv1.z); p.u[7]=f2bf(xv1.w);
      *(uint4*)&xt[(it+1)&1][xr*72 + xk] = p.q;
      ushort* d = &bt[(it+1)&1][wn*72 + wk];
      *(uint4*)d=wb0; *(uint4*)(d+8)=wb1; *(uint4*)(d+16)=wb2; *(uint4*)(d+24)=wb3;
    }
    if (it < 62){
      const int kt = (it+2)*64;
      xv0 = *(const float4*)&x[(size_t)(row0+xr)*XD_ + kt + xk];
      xv1 = *(const float4*)&x[(size_t)(row0+xr)*XD_ + kt + xk + 4];
      const ushort* s = &WXT[(size_t)(ncol0+wn)*XD_ + kt + wk];
      wb0=*(const uint4*)s; wb1=*(const uint4*)(s+8); wb2=*(const uint4*)(s+16); wb3=*(const uint4*)(s+24);
    }
    const ushort* xb = &xt[it&1][(rt*16+l15)*72];
    const ushort* bb = &bt[it&1][0];
    #pragma unroll
    for (int h = 0; h < 2; ++h){
      short8_t a = *(const short8_t*)(xb + h*32 + kq8);
      #pragma unroll
      for (int c = 0; c < 4; ++c){
        short8_t b = *(const short8_t*)(bb + ((cb4+c)*16+l15)*72 + h*32 + kq8);
        acc[c] = MFMA16(a, b, acc[c]);
      }
    }
  }
  #pragma unroll
  for (int c = 0; c < 4; ++c){
    int jl = (cb4+c)*16 + l15;
    #pragma unroll
    for (int r = 0; r < 4; ++r){
      int row = row0 + rt*16 + rq + r;
      float v = acc[c][r];
      if (bn == 0) cneg[(size_t)row*H_ + jl] = 2.0f*(cb[jl] - v);
      else         h1pre[(size_t)row*H_ + jl] = v + q0[jl];
    }
  }
}

// ---------------- 128-dim Langevin: yc state in f32 MFMA accumulators ----------------
__global__ __launch_bounds__(512) void k_lv2(
    const ushort* __restrict__ M2bf, const ushort* __restrict__ GGr,
    const float* __restrict__ y0c0, const ushort* __restrict__ NWR,
    const float* __restrict__ b1, const float* __restrict__ r0v,
    const float* __restrict__ cneg,
    ushort* __restrict__ hfin_bf, float* __restrict__ capre){
  __shared__ __align__(16) ushort abuf[16*136];
  __shared__ __align__(16) ushort glbuf[16*136];
  const int t = threadIdx.x, lane = t & 63, w = t >> 6;
  const int l15 = lane & 15, kq8 = (lane >> 4)*8, rq = (lane >> 4)*4;
  const int b0 = blockIdx.x * 16;
  const int myc = w*16 + l15;
  const int col2 = w*32 + l15;

  f32x4_t acc[2];
  #pragma unroll
  for (int nf = 0; nf < 2; ++nf)
    #pragma unroll
    for (int r = 0; r < 4; ++r)
      acc[nf][r] = y0c0[(size_t)(b0+rq+r)*256 + col2 + nf*16];
  float cn[4];
  #pragma unroll
  for (int r = 0; r < 4; ++r) cn[r] = cneg[(size_t)(b0+rq+r)*H_ + myc];
  float bb2[2];
  bb2[0] = (w < 4) ? b1[col2] : 0.0f;
  bb2[1] = (w < 4) ? b1[col2+16] : 0.0f;
  ushort nx[8];
  #pragma unroll
  for (int nf = 0; nf < 2; ++nf)
    #pragma unroll
    for (int r = 0; r < 4; ++r)
      nx[nf*4+r] = NWR[(size_t)(b0+rq+r)*256 + col2 + nf*16];

  #pragma unroll 1
  for (int s = 0; s < 10; ++s){
    if (w < 4){
      #pragma unroll
      for (int nf = 0; nf < 2; ++nf)
        #pragma unroll
        for (int r = 0; r < 4; ++r)
          abuf[(rq+r)*136 + col2 + nf*16] = f2bf(fmaxf(acc[nf][r] + bb2[nf], 0.0f));
    }
    __syncthreads();
    f32x4_t g2 = {};
    #pragma unroll
    for (int h = 0; h < 4; ++h){
      short8_t a = *(const short8_t*)&abuf[l15*136 + h*32 + kq8];
      short8_t b = *(const short8_t*)&M2bf[(size_t)myc*H_ + h*32 + kq8];
      g2 = MFMA16(a, b, g2);
    }
    #pragma unroll
    for (int r = 0; r < 4; ++r){
      float g = (abuf[(rq+r)*136 + myc] != 0) ? (g2[r] + cn[r]) : 0.0f;
      glbuf[(rq+r)*136 + myc] = f2bf(g);
    }
    __syncthreads();
    #pragma unroll
    for (int nf = 0; nf < 2; ++nf)
      #pragma unroll
      for (int h = 0; h < 4; ++h){
        short8_t a = *(const short8_t*)&glbuf[l15*136 + h*32 + kq8];
        short8_t b = *(const short8_t*)&GGr[(size_t)(col2 + nf*16)*H_ + h*32 + kq8];
        acc[nf] = MFMA16(a, b, acc[nf]);
      }
    #pragma unroll
    for (int nf = 0; nf < 2; ++nf)
      #pragma unroll
      for (int r = 0; r < 4; ++r)
        acc[nf][r] += bf2f(nx[nf*4+r]);
    if (s < 9){
      #pragma unroll
      for (int nf = 0; nf < 2; ++nf)
        #pragma unroll
        for (int r = 0; r < 4; ++r)
          nx[nf*4+r] = NWR[(size_t)(s+1)*2097152 + (size_t)(b0+rq+r)*256 + col2 + nf*16];
    }
    __syncthreads();
  }
  if (w < 4){
    #pragma unroll
    for (int nf = 0; nf < 2; ++nf)
      #pragma unroll
      for (int r = 0; r < 4; ++r)
        hfin_bf[(size_t)(b0+rq+r)*H_ + col2 + nf*16] = f2bf(fmaxf(acc[nf][r] + bb2[nf], 0.0f));
  } else {
    #pragma unroll
    for (int nf = 0; nf < 2; ++nf)
      #pragma unroll
      for (int r = 0; r < 4; ++r)
        capre[(size_t)(b0+rq+r)*H_ + (col2 + nf*16 - 128)] = acc[nf][r] + r0v[col2 + nf*16 - 128];
  }
}

// ---------------- x_recon (MFMA): out = hfin @ W2^T + b2 ----------------
__global__ __launch_bounds__(256) void k_xrecon_mfma(
    const ushort* __restrict__ hfin_bf, const ushort* __restrict__ W2bf,
    const float* __restrict__ b2, float* __restrict__ out){
  __shared__ __align__(16) ushort at[64*136];
  __shared__ __align__(16) ushort bt[128*136];
  const int tid = threadIdx.x, lane = tid & 63, w = tid >> 6;
  const int bm = blockIdx.x >> 5, bn = blockIdx.x & 31;
  const int row0 = bm*64, c0 = bn*128;
  const int l15 = lane & 15, kq8 = (lane >> 4)*8, rq = (lane >> 4)*4;
  { int r = tid >> 2, kq = (tid & 3)*32;
    const ushort* src = &hfin_bf[(size_t)(row0 + r)*H_ + kq];
    #pragma unroll
    for (int i = 0; i < 4; ++i) *(uint4*)&at[r*136 + kq + 8*i] = *(const uint4*)(src + 8*i);
  }
  { int n = tid >> 1, kh = (tid & 1)*64;
    const ushort* src = &W2bf[(size_t)(c0 + n)*H_ + kh];
    #pragma unroll
    for (int i = 0; i < 8; ++i) *(uint4*)&bt[n*136 + kh + 8*i] = *(const uint4*)(src + 8*i);
  }
  __syncthreads();
  f32x4_t acc[8] = {};
  #pragma unroll
  for (int k = 0; k < 4; ++k){
    short8_t a = *(const short8_t*)&at[(w*16 + l15)*136 + k*32 + kq8];
    #pragma unroll
    for (int nf = 0; nf < 8; ++nf){
      short8_t b = *(const short8_t*)&bt[(nf*16 + l15)*136 + k*32 + kq8];
      acc[nf] = MFMA16(a, b, acc[nf]);
    }
  }
  #pragma unroll
  for (int nf = 0; nf < 8; ++nf){
    int c = c0 + nf*16 + l15;
    float bbv = b2[c];
    #pragma unroll
    for (int r = 0; r < 4; ++r){
      int row = row0 + w*16 + rq + r;
      out[(size_t)row*XD_ + c] = acc[nf][r] + bbv;
    }
  }
}

// ---------------- per-row transformer tail -> y_pred ----------------
__device__ __forceinline__ float wsum64(float v){
  #pragma unroll
  for (int off = 32; off > 0; off >>= 1) v += __shfl_xor(v, off, 64);
  return v;
}

__global__ __launch_bounds__(256) void k_tail(
    const float* __restrict__ h1pre, const float* __restrict__ capre,
    const float* __restrict__ ln1g, const float* __restrict__ ln1b,
    const float* __restrict__ ln2g, const float* __restrict__ ln2b,
    const float* __restrict__ ln3g, const float* __restrict__ ln3b,
    const float* __restrict__ fW1, const float* __restrict__ fb1,
    const float* __restrict__ fW2, const float* __restrict__ fb2,
    const float* __restrict__ outW, const float* __restrict__ outb,
    float* __restrict__ y){
  __shared__ float sh2[4][128];
  __shared__ float st1[4][128];
  const int tid = threadIdx.x;
  const int w = tid >> 6;
  const int l = tid & 63;
  const int b = blockIdx.x * 4 + w;
  const float* hp = h1pre + (size_t)b * H_;
  const float* cp = capre + (size_t)b * H_;
  float x0 = hp[l], x1 = hp[l+64];
  float m = wsum64(x0 + x1) * (1.0f/128.0f);
  float d0 = x0 - m, d1 = x1 - m;
  float v = wsum64(d0*d0 + d1*d1) * (1.0f/128.0f);
  float rs = rsqrtf(v + 1e-5f);
  float h1a = d0 * rs * ln1g[l]    + ln1b[l];
  float h1b = d1 * rs * ln1g[l+64] + ln1b[l+64];
  x0 = h1a + cp[l]; x1 = h1b + cp[l+64];
  m = wsum64(x0 + x1) * (1.0f/128.0f);
  d0 = x0 - m; d1 = x1 - m;
  v = wsum64(d0*d0 + d1*d1) * (1.0f/128.0f);
  rs = rsqrtf(v + 1e-5f);
  float h2a = d0 * rs * ln2g[l]    + ln2b[l];
  float h2b = d1 * rs * ln2g[l+64] + ln2b[l+64];
  sh2[w][l] = h2a; sh2[w][l+64] = h2b;
  __syncthreads();
  float ta = fb1[l], tb = fb1[l+64];
  #pragma unroll 8
  for (int m4 = 0; m4 < H_; m4 += 4){
    float4 hv = *(const float4*)&sh2[w][m4];
    float4 wa = *(const float4*)&fW1[(size_t)l*H_ + m4];
    float4 wb = *(const float4*)&fW1[(size_t)(l+64)*H_ + m4];
    ta = fmaf(wa.x, hv.x, ta); ta = fmaf(wa.y, hv.y, ta); ta = fmaf(wa.z, hv.z, ta); ta = fmaf(wa.w, hv.w, ta);
    tb = fmaf(wb.x, hv.x, tb); tb = fmaf(wb.y, hv.y, tb); tb = fmaf(wb.z, hv.z, tb); tb = fmaf(wb.w, hv.w, tb);
  }
  ta = fmaxf(ta, 0.0f); tb = fmaxf(tb, 0.0f);
  st1[w][l] = ta; st1[w][l+64] = tb;
  __syncthreads();
  float fa = fb2[l], fbv = fb2[l+64];
  #pragma unroll 8
  for (int m4 = 0; m4 < H_; m4 += 4){
    float4 tv = *(const float4*)&st1[w][m4];
    float4 wa = *(const float4*)&fW2[(size_t)l*H_ + m4];
    float4 wb = *(const float4*)&fW2[(size_t)(l+64)*H_ + m4];
    fa  = fmaf(wa.x, tv.x, fa);  fa  = fmaf(wa.y, tv.y, fa);  fa  = fmaf(wa.z, tv.z, fa);  fa  = fmaf(wa.w, tv.w, fa);
    fbv = fmaf(wb.x, tv.x, fbv); fbv = fmaf(wb.y, tv.y, fbv); fbv = fmaf(wb.z, tv.z, fbv); fbv = fmaf(wb.w, tv.w, fbv);
  }
  x0 = h2a + fa; x1 = h2b + fbv;
  m = wsum64(x0 + x1) * (1.0f/128.0f);
  d0 = x0 - m; d1 = x1 - m;
  v = wsum64(d0*d0 + d1*d1) * (1.0f/128.0f);
  rs = rsqrtf(v + 1e-5f);
  float h3a = d0 * rs * ln3g[l]    + ln3b[l];
  float h3b = d1 * rs * ln3g[l+64] + ln3b[l+64];
  float py = wsum64(outW[l]*h3a + outW[l+64]*h3b);
  if (l == 0) y[b] = py + outb[0];
}

// ---------------- host ----------------
extern "C" void kernel_launch(void* const* d_in, const int* in_sizes, int n_in,
                              void* d_out, int out_size, void* d_ws, size_t ws_size,
                              hipStream_t stream){
  const float* x      = (const float*)d_in[0];
  const float* pxW1   = (const float*)d_in[1];
  const float* pxb1   = (const float*)d_in[2];
  const float* pxW2   = (const float*)d_in[3];
  const float* pxb2   = (const float*)d_in[4];
  const float* embW   = (const float*)d_in[5];
  const float* embb   = (const float*)d_in[6];
  const float* xpW    = (const float*)d_in[7];
  const float* xpb    = (const float*)d_in[8];
  const float* zpW    = (const float*)d_in[9];
  const float* zpb    = (const float*)d_in[10];
  const float* saWqkv = (const float*)d_in[11];
  const float* sabqkv = (const float*)d_in[12];
  const float* saWo   = (const float*)d_in[13];
  const float* sabo   = (const float*)d_in[14];
  const float* caWqkv = (const float*)d_in[15];
  const float* cabqkv = (const float*)d_in[16];
  const float* caWo   = (const float*)d_in[17];
  const float* cabo   = (const float*)d_in[18];
  const float* fW1    = (const float*)d_in[19];
  const float* fb1    = (const float*)d_in[20];
  const float* fW2    = (const float*)d_in[21];
  const float* fb2    = (const float*)d_in[22];
  const float* ln1g   = (const float*)d_in[23];
  const float* ln1b   = (const float*)d_in[24];
  const float* ln2g   = (const float*)d_in[25];
  const float* ln2b   = (const float*)d_in[26];
  const float* ln3g   = (const float*)d_in[27];
  const float* ln3b   = (const float*)d_in[28];
  const float* outW   = (const float*)d_in[29];
  const float* outb   = (const float*)d_in[30];
  (void)in_sizes; (void)n_in; (void)out_size; (void)ws_size;

  float* ws    = (float*)d_ws;
  float* cneg  = ws;                          // 1048576
  float* h1pre = cneg + (size_t)B_*H_;        // 1048576
  float* capre = h1pre + (size_t)B_*H_;       // 1048576
  float* Rm    = capre + (size_t)B_*H_;       // 131072
  float* Mm    = Rm + (size_t)H_*ZD_;         // 16384
  float* Sm    = Mm + H_*H_;                  // 16384
  float* Um    = Sm + H_*H_;                  // 16384
  float* Tm    = Um + H_*H_;                  // 8192
  float* vs0   = Tm + H_*XE_;
  float* vu0   = vs0 + H_;
  float* vt0   = vu0 + H_;
  float* vq0   = vt0 + H_;
  float* vr0   = vq0 + H_;
  float* vcb   = vr0 + H_;
  uint32_t* dkeys = (uint32_t*)(vcb + H_);    // 32 u32
  float* y0c0  = (float*)(dkeys + 32);        // 2097152 f32
  ushort* WXT   = (ushort*)(y0c0 + (size_t)B_*256);  // 1048576
  ushort* W2bf  = WXT + (size_t)256*XD_;      // 524288
  ushort* Mbf   = W2bf + (size_t)XD_*H_;      // 16384 (=2M)
  ushort* FBT   = Mbf + H_*H_;                // 262144
  ushort* GGr   = FBT + (size_t)256*ZD_;      // 32768
  ushort* hfin  = GGr + (size_t)256*H_;       // 1048576
  ushort* NWR   = hfin + (size_t)B_*H_;       // 20971520 (10 x 8192 x 256)

  float* xre   = (float*)d_out;
  float* ypred = xre + (size_t)B_*XD_;

  k_prepA   <<<512,  64, 0, stream>>>(saWo, saWqkv, caWo, caWqkv, Sm, Um);
  k_prepB   <<<6,    64, 0, stream>>>(saWo, sabqkv, sabo, caWo, cabqkv, cabo, pxW2, pxb2,
                                      vs0, vu0, vcb, dkeys);
  k_prepM   <<<256,  64, 0, stream>>>(pxW2, Mm);
  k_prepTR  <<<2180, 64, 0, stream>>>(Sm, Um, xpW, zpW, xpb, zpb, vs0, vu0, Tm, Rm, vt0, vr0);
  k_prepWXT <<<4096, 256, 0, stream>>>(pxW2, Tm, embW, embb, vt0, WXT, vq0);
  k_conv    <<<3136, 256, 0, stream>>>(pxW2, pxW1, Mm, Rm, W2bf, Mbf, FBT);
  k_prepG   <<<512,  64, 0, stream>>>(pxW1, Rm, GGr);
  k_noiseproj <<<1408, 512, 0, stream>>>(FBT, dkeys, y0c0, NWR);
  k_xpass_mfma <<<512, 256, 0, stream>>>(x, WXT, vcb, vq0, cneg, h1pre);
  k_lv2     <<<512, 512, 0, stream>>>(Mbf, GGr, y0c0, NWR, pxb1, vr0, cneg, hfin, capre);
  k_xrecon_mfma <<<4096, 256, 0, stream>>>(hfin, W2bf, pxb2, xre);
  k_tail    <<<2048, 256, 0, stream>>>(h1pre, capre, ln1g, ln1b, ln2g, ln2b, ln3g, ln3b,
                                       fW1, fb1, fW2, fb2, outW, outb, ypred);
}

// Round 12
// 933.436 us; speedup vs baseline: 1.0233x; 1.0233x over previous
//
#include <hip/hip_runtime.h>
#include <hip/hip_bf16.h>
#include <cstdint>
#include <cstddef>
#include <cmath>

#define B_     8192
#define XD_    4096
#define ZD_    1024
#define XE_    64
#define H_     128
#define ZN_    (B_*ZD_)

typedef __attribute__((ext_vector_type(8))) short short8_t;   // 8 x bf16 (4 VGPR)
typedef __attribute__((ext_vector_type(4))) float f32x4_t;    // MFMA accumulator
#define MFMA16(a,b,c) __builtin_amdgcn_mfma_f32_16x16x32_bf16((a),(b),(c),0,0,0)

// ---------------- threefry2x32 (bit-exact vs JAX, partitionable mode — validated R1-R11) ----
__host__ __device__ __forceinline__ uint32_t rotl32_(uint32_t x, int r){
#ifdef __HIP_DEVICE_COMPILE__
  return __builtin_rotateleft32(x, (uint32_t)r);
#else
  return (x<<r)|(x>>(32-r));
#endif
}

__host__ __device__ __forceinline__ void tf2x32(uint32_t k0, uint32_t k1,
                                                uint32_t x0, uint32_t x1,
                                                uint32_t* o0, uint32_t* o1){
  uint32_t k2 = k0 ^ k1 ^ 0x1BD11BDAu;
  x0 += k0; x1 += k1;
  x0 += x1; x1 = rotl32_(x1,13); x1 ^= x0;
  x0 += x1; x1 = rotl32_(x1,15); x1 ^= x0;
  x0 += x1; x1 = rotl32_(x1,26); x1 ^= x0;
  x0 += x1; x1 = rotl32_(x1, 6); x1 ^= x0;
  x0 += k1; x1 += k2 + 1u;
  x0 += x1; x1 = rotl32_(x1,17); x1 ^= x0;
  x0 += x1; x1 = rotl32_(x1,29); x1 ^= x0;
  x0 += x1; x1 = rotl32_(x1,16); x1 ^= x0;
  x0 += x1; x1 = rotl32_(x1,24); x1 ^= x0;
  x0 += k2; x1 += k0 + 2u;
  x0 += x1; x1 = rotl32_(x1,13); x1 ^= x0;
  x0 += x1; x1 = rotl32_(x1,15); x1 ^= x0;
  x0 += x1; x1 = rotl32_(x1,26); x1 ^= x0;
  x0 += x1; x1 = rotl32_(x1, 6); x1 ^= x0;
  x0 += k0; x1 += k1 + 3u;
  x0 += x1; x1 = rotl32_(x1,17); x1 ^= x0;
  x0 += x1; x1 = rotl32_(x1,29); x1 ^= x0;
  x0 += x1; x1 = rotl32_(x1,16); x1 ^= x0;
  x0 += x1; x1 = rotl32_(x1,24); x1 ^= x0;
  x0 += k1; x1 += k2 + 4u;
  x0 += x1; x1 = rotl32_(x1,13); x1 ^= x0;
  x0 += x1; x1 = rotl32_(x1,15); x1 ^= x0;
  x0 += x1; x1 = rotl32_(x1,26); x1 ^= x0;
  x0 += x1; x1 = rotl32_(x1, 6); x1 ^= x0;
  x0 += k2; x1 += k0 + 5u;
  *o0 = x0; *o1 = x1;
}

// XLA ErfInv32; fast v_log (validated R8-R11, absmax unchanged)
__device__ __forceinline__ float erfinv_(float x){
  float w = -__logf(fmaf(-x, x, 1.0f));
  float p;
  if (w < 5.0f){
    w -= 2.5f;
    p = 2.81022636e-08f;
    p = fmaf(p, w, 3.43273939e-07f);
    p = fmaf(p, w, -3.5233877e-06f);
    p = fmaf(p, w, -4.39150654e-06f);
    p = fmaf(p, w, 0.00021858087f);
    p = fmaf(p, w, -0.00125372503f);
    p = fmaf(p, w, -0.00417768164f);
    p = fmaf(p, w, 0.246640727f);
    p = fmaf(p, w, 1.50140941f);
  } else {
    w = sqrtf(w) - 3.0f;
    p = -0.000200214257f;
    p = fmaf(p, w, 0.000100950558f);
    p = fmaf(p, w, 0.00134934322f);
    p = fmaf(p, w, -0.00367342844f);
    p = fmaf(p, w, 0.00573950773f);
    p = fmaf(p, w, -0.0076224613f);
    p = fmaf(p, w, 0.00943887047f);
    p = fmaf(p, w, 1.00167406f);
    p = fmaf(p, w, 2.83297682f);
  }
  return p * x;
}

__device__ __forceinline__ float bits_to_normal(uint32_t bits){
  float f = __uint_as_float((bits >> 9) | 0x3f800000u) - 1.0f;
  float u = fmaxf(-0.99999994f, fmaf(f, 2.0f, -0.99999994f));
  return 1.41421356f * erfinv_(u);
}

__device__ __forceinline__ float rng_normal(uint32_t k0, uint32_t k1, uint32_t idx){
  uint32_t o0, o1; tf2x32(k0, k1, 0u, idx, &o0, &o1);
  return bits_to_normal(o0 ^ o1);
}

__device__ __forceinline__ ushort f2bf(float f){
  return __builtin_bit_cast(ushort, __float2bfloat16(f));
}
__device__ __forceinline__ float bf2f(ushort u){ return __uint_as_float(((uint32_t)u) << 16); }

// 8 bf16 normals (counters base..base+7) into a uint4 (registers)
__device__ __forceinline__ void gen8(uint32_t k0, uint32_t k1, uint32_t base, uint4* g){
  union { ushort u[8]; uint4 q; } pk;
  #pragma unroll
  for (int j = 0; j < 8; ++j) pk.u[j] = f2bf(rng_normal(k0,k1,base+(uint32_t)j));
  *g = pk.q;
}

// ---------------- weight-prep kernels (f32) ----------------
__global__ void k_prepA(const float* __restrict__ saWo, const float* __restrict__ saWqkv,
                        const float* __restrict__ caWo, const float* __restrict__ caWqkv,
                        float* __restrict__ S, float* __restrict__ U){
  int blk = blockIdx.x, tid = threadIdx.x;
  int idx = (blk & 255) * 64 + tid;
  int i = idx >> 7, j = idx & 127;
  if (blk < 256){
    float acc = (i == j) ? 1.0f : 0.0f;
    for (int k = 0; k < H_; ++k) acc += saWo[i*H_ + k] * saWqkv[(2*H_ + k)*H_ + j];
    S[idx] = acc;
  } else {
    float acc = 0.0f;
    for (int k = 0; k < H_; ++k) acc += caWo[i*H_ + k] * caWqkv[(2*H_ + k)*H_ + j];
    U[idx] = acc;
  }
}

__global__ void k_prepB(const float* __restrict__ saWo, const float* __restrict__ sabqkv, const float* __restrict__ sabo,
                        const float* __restrict__ caWo, const float* __restrict__ cabqkv, const float* __restrict__ cabo,
                        const float* __restrict__ W2, const float* __restrict__ pb2,
                        float* __restrict__ s0, float* __restrict__ u0, float* __restrict__ cb,
                        uint32_t* __restrict__ dkeys){
  int blk = blockIdx.x, tid = threadIdx.x;
  if (blk == 0 && tid == 0){
    for (uint32_t i = 0; i < 11; ++i){
      uint32_t a, b; tf2x32(0u, 42u, 0u, i, &a, &b);
      dkeys[2*i] = a; dkeys[2*i+1] = b;
    }
  }
  if (blk < 2){
    int i = blk*64 + tid;
    float acc = sabo[i];
    for (int k = 0; k < H_; ++k) acc += saWo[i*H_ + k] * sabqkv[2*H_ + k];
    s0[i] = acc;
  } else if (blk < 4){
    int i = (blk-2)*64 + tid;
    float acc = cabo[i];
    for (int k = 0; k < H_; ++k) acc += caWo[i*H_ + k] * cabqkv[2*H_ + k];
    u0[i] = acc;
  } else {
    int j = (blk-4)*64 + tid;
    float acc = 0.0f;
    for (int c = 0; c < XD_; ++c) acc += pb2[c] * W2[(size_t)c*H_ + j];
    cb[j] = acc;
  }
}

__global__ void k_prepTR(const float* __restrict__ S, const float* __restrict__ U,
                         const float* __restrict__ xpW, const float* __restrict__ zpW,
                         const float* __restrict__ xpb, const float* __restrict__ zpb,
                         const float* __restrict__ s0, const float* __restrict__ u0,
                         float* __restrict__ T, float* __restrict__ R,
                         float* __restrict__ t0, float* __restrict__ r0v){
  int blk = blockIdx.x, tid = threadIdx.x;
  if (blk < 128){
    int idx = blk*64 + tid;
    int i = idx >> 6, e = idx & 63;
    float acc = 0.0f;
    for (int m = 0; m < H_; ++m) acc += S[i*H_ + m] * xpW[m*XE_ + e];
    T[idx] = acc;
  } else if (blk < 2176){
    int idx = (blk-128)*64 + tid;
    int i = idx >> 10, k = idx & 1023;
    float acc = 0.0f;
    for (int m = 0; m < H_; ++m) acc += U[i*H_ + m] * zpW[(size_t)m*ZD_ + k];
    R[idx] = acc;
  } else if (blk < 2178){
    int i = (blk-2176)*64 + tid;
    float acc = s0[i];
    for (int m = 0; m < H_; ++m) acc += S[i*H_ + m] * xpb[m];
    t0[i] = acc;
  } else {
    int i = (blk-2178)*64 + tid;
    float acc = u0[i];
    for (int m = 0; m < H_; ++m) acc += U[i*H_ + m] * zpb[m];
    r0v[i] = acc;
  }
}

// split-K=8 partials for M = W2^T W2 (K=4096) and G/Gr (K=1024).
// R11 post-mortem: old single-chain versions had 16K/32K threads total, fully
// latency-exposed (1-2 waves/SIMD). 393K work items now. Deterministic 2-stage
// (fold in k_conv) — no float atomics.
__global__ void k_prepMG_part(const float* __restrict__ W2, const float* __restrict__ W1,
                              const float* __restrict__ R,
                              float* __restrict__ Mpart, float* __restrict__ Gpart){
  int gid = blockIdx.x*256 + threadIdx.x;   // 393216
  if (gid < 131072){
    int slice = gid >> 14, i = gid & 16383;
    int j1 = i >> 7, j2 = i & 127;
    int c0 = slice*512;
    float acc = 0.0f;
    for (int c = c0; c < c0+512; ++c)
      acc += W2[(size_t)c*H_ + j1] * W2[(size_t)c*H_ + j2];
    Mpart[(size_t)slice*16384 + i] = acc;
  } else {
    int g = gid - 131072;
    int slice = g >> 15, i2 = g & 32767;
    int i = i2 >> 7, k = i2 & 127;
    int m0 = slice*128;
    float acc = 0.0f;
    if (i < 128){
      for (int m = m0; m < m0+128; ++m)
        acc += W1[(size_t)i*ZD_ + m] * W1[(size_t)k*ZD_ + m];
    } else {
      for (int m = m0; m < m0+128; ++m)
        acc += W1[(size_t)k*ZD_ + m] * R[(size_t)(i-128)*ZD_ + m];
    }
    Gpart[(size_t)slice*32768 + i2] = acc;
  }
}

__global__ void k_prepWXT(const float* __restrict__ W2, const float* __restrict__ T,
                          const float* __restrict__ embW, const float* __restrict__ embb,
                          const float* __restrict__ t0,
                          ushort* __restrict__ WXT, float* __restrict__ q0){
  int idx = blockIdx.x*256 + threadIdx.x;   // 1048576
  int j = idx >> 12, c = idx & 4095;
  float v;
  if (j < H_) v = W2[(size_t)c*H_ + j];
  else {
    int i = j - H_;
    float acc = 0.0f;
    for (int e = 0; e < XE_; ++e) acc += T[i*XE_ + e] * embW[(size_t)e*XD_ + c];
    v = acc;
  }
  WXT[idx] = f2bf(v);
  if (idx < H_){
    float acc = t0[idx];
    for (int e = 0; e < XE_; ++e) acc += T[idx*XE_ + e] * embb[e];
    q0[idx] = acc;
  }
}

// W2bf[524288]; Mbf = f2bf(2*sum Mpart) [16384]; FBT=[W1;R] [262144]; GGr = f2bf(-0.005*sum Gpart) [32768]
__global__ void k_conv(const float* __restrict__ W2, const float* __restrict__ W1,
                       const float* __restrict__ R,
                       const float* __restrict__ Mpart, const float* __restrict__ Gpart,
                       ushort* __restrict__ W2bf, ushort* __restrict__ Mbf,
                       ushort* __restrict__ FBT, ushort* __restrict__ GGr){
  int idx = blockIdx.x*256 + threadIdx.x;   // 835584
  if (idx < 524288) W2bf[idx] = f2bf(W2[idx]);
  else if (idx < 540672){
    int i = idx - 524288;
    float s = 0.0f;
    #pragma unroll
    for (int p = 0; p < 8; ++p) s += Mpart[(size_t)p*16384 + i];
    Mbf[i] = f2bf(2.0f*s);
  } else if (idx < 802816){
    int i = idx - 540672; int j = i >> 10, k = i & 1023;
    FBT[i] = f2bf(j < H_ ? W1[j*ZD_ + k] : R[(size_t)(j-H_)*ZD_ + k]);
  } else {
    int i = idx - 802816;
    float s = 0.0f;
    #pragma unroll
    for (int p = 0; p < 8; ++p) s += Gpart[(size_t)p*32768 + i];
    GGr[i] = f2bf(-0.005f*s);
  }
}

// ---------------- noise projection: pass p rows [8192][1024] RNG @ FBT^T -> [8192][256]
// R9/R11 post-mortem: LDS-staged A cost 1.7-2.2x the RNG VALU floor (barriers +
// staging on critical path; occupancy fixes added VALU). Key insight: the MFMA
// A-fragment layout means lane (l15, q=lane>>4) needs EXACTLY normals
// idx=(row0+l15)*1024+it*64+h*32+q*8+j -> each wave generates its own 16x64
// A-tile IN REGISTERS. Zero LDS, zero barriers, zero inter-wave coupling; B from
// L2 (as before). acc[16]=64 AGPR + ~55 VGPR -> 3-4 waves/SIMD; RNG VALU chain
// overlaps MFMA + B-load latency within-wave and across waves.
__global__ __launch_bounds__(256) void k_noiseproj(
    const ushort* __restrict__ FBT, const uint32_t* __restrict__ dkeys,
    float* __restrict__ y0c0, ushort* __restrict__ NWR){
  const int t = threadIdx.x, lane = t & 63, w = t >> 6;
  const int l15 = lane & 15, kq8 = (lane >> 4)*8, rq = (lane >> 4)*4;
  const int gwid = blockIdx.x*4 + w;         // 0..5631
  const int p = gwid >> 9, mb = gwid & 511;  // 11 passes x 512 row-tiles of 16
  const int row0 = mb*16;
  const uint32_t k0 = dkeys[2*p], k1 = dkeys[2*p+1];
  const uint32_t rbase = (uint32_t)(row0 + l15)*1024u + (uint32_t)kq8;
  f32x4_t acc[16] = {};
  #pragma unroll 1
  for (int it = 0; it < 16; ++it){
    uint4 g0, g1;
    gen8(k0, k1, rbase + (uint32_t)(it*64), &g0);        // h=0
    gen8(k0, k1, rbase + (uint32_t)(it*64 + 32), &g1);   // h=1
    short8_t a0 = __builtin_bit_cast(short8_t, g0);
    short8_t a1 = __builtin_bit_cast(short8_t, g1);
    const ushort* fb = &FBT[(size_t)l15*ZD_ + it*64 + kq8];
    #pragma unroll
    for (int cf = 0; cf < 16; ++cf){
      short8_t b0 = *(const short8_t*)(fb + (size_t)cf*16*ZD_);
      acc[cf] = MFMA16(a0, b0, acc[cf]);
    }
    #pragma unroll
    for (int cf = 0; cf < 16; ++cf){
      short8_t b1 = *(const short8_t*)(fb + (size_t)cf*16*ZD_ + 32);
      acc[cf] = MFMA16(a1, b1, acc[cf]);
    }
  }
  #pragma unroll
  for (int cf = 0; cf < 16; ++cf){
    int col = cf*16 + l15;
    #pragma unroll
    for (int r = 0; r < 4; ++r){
      int row = row0 + rq + r;
      float v = acc[cf][r];
      if (p == 0) y0c0[(size_t)row*256 + col] = v;
      else NWR[(size_t)(p-1)*2097152 + (size_t)row*256 + col] = f2bf(0.1f*v);
    }
  }
}

// ---------------- x-pass (MFMA, dbuf, 1 barrier/iter): [cneg | h1pre] = x @ WXT^T ----
// BM=32, BN=128, grid 512, 256 thr. Carried-register prefetch (R8-proven).
__global__ __launch_bounds__(256) void k_xpass_mfma(
    const float* __restrict__ x, const ushort* __restrict__ WXT,
    const float* __restrict__ cb, const float* __restrict__ q0,
    float* __restrict__ cneg, float* __restrict__ h1pre){
  __shared__ __align__(16) ushort xt[2][32*72];
  __shared__ __align__(16) ushort bt[2][128*72];
  const int t = threadIdx.x, lane = t & 63, w = t >> 6;
  const int bm = blockIdx.x >> 1, bn = blockIdx.x & 1;
  const int row0 = bm*32, ncol0 = bn*128;
  const int l15 = lane & 15, kq8 = (lane >> 4)*8, rq = (lane >> 4)*4;
  const int rt = w & 1, cb4 = (w >> 1)*4;
  const int xr = t >> 3, xk = (t & 7)*8;
  const int wn = t >> 1, wk = (t & 1)*32;
  f32x4_t acc[4] = {};
  {
    float4 v0 = *(const float4*)&x[(size_t)(row0+xr)*XD_ + xk];
    float4 v1 = *(const float4*)&x[(size_t)(row0+xr)*XD_ + xk + 4];
    union { ushort u[8]; uint4 q; } p;
    p.u[0]=f2bf(v0.x); p.u[1]=f2bf(v0.y); p.u[2]=f2bf(v0.z); p.u[3]=f2bf(v0.w);
    p.u[4]=f2bf(v1.x); p.u[5]=f2bf(v1.y); p.u[6]=f2bf(v1.z); p.u[7]=f2bf(v1.w);
    *(uint4*)&xt[0][xr*72 + xk] = p.q;
    const ushort* s = &WXT[(size_t)(ncol0+wn)*XD_ + wk];
    uint4 b0v=*(const uint4*)s, b1v=*(const uint4*)(s+8), b2v=*(const uint4*)(s+16), b3v=*(const uint4*)(s+24);
    ushort* d = &bt[0][wn*72 + wk];
    *(uint4*)d=b0v; *(uint4*)(d+8)=b1v; *(uint4*)(d+16)=b2v; *(uint4*)(d+24)=b3v;
  }
  float4 xv0, xv1; uint4 wb0, wb1, wb2, wb3;
  {
    xv0 = *(const float4*)&x[(size_t)(row0+xr)*XD_ + 64 + xk];
    xv1 = *(const float4*)&x[(size_t)(row0+xr)*XD_ + 64 + xk + 4];
    const ushort* s = &WXT[(size_t)(ncol0+wn)*XD_ + 64 + wk];
    wb0=*(const uint4*)s; wb1=*(const uint4*)(s+8); wb2=*(const uint4*)(s+16); wb3=*(const uint4*)(s+24);
  }
  #pragma unroll 1
  for (int it = 0; it < 64; ++it){
    __syncthreads();
    if (it < 63){
      union { ushort u[8]; uint4 q; } p;
      p.u[0]=f2bf(xv0.x); p.u[1]=f2bf(xv0.y); p.u[2]=f2bf(xv0.z); p.u[3]=f2bf(xv0.w);
      p.u[4]=f2bf(xv1.x); p.u[5]=f2bf(xv1.y); p.u[6]=f2bf(xv1.z); p.u[7]=f2bf(xv1.w);
      *(uint4*)&xt[(it+1)&1][xr*72 + xk] = p.q;
      ushort* d = &bt[(it+1)&1][wn*72 + wk];
      *(uint4*)d=wb0; *(uint4*)(d+8)=wb1; *(uint4*)(d+16)=wb2; *(uint4*)(d+24)=wb3;
    }
    if (it < 62){
      const int kt = (it+2)*64;
      xv0 = *(const float4*)&x[(size_t)(row0+xr)*XD_ + kt + xk];
      xv1 = *(const float4*)&x[(size_t)(row0+xr)*XD_ + kt + xk + 4];
      const ushort* s = &WXT[(size_t)(ncol0+wn)*XD_ + kt + wk];
      wb0=*(const uint4*)s; wb1=*(const uint4*)(s+8); wb2=*(const uint4*)(s+16); wb3=*(const uint4*)(s+24);
    }
    const ushort* xb = &xt[it&1][(rt*16+l15)*72];
    const ushort* bb = &bt[it&1][0];
    #pragma unroll
    for (int h = 0; h < 2; ++h){
      short8_t a = *(const short8_t*)(xb + h*32 + kq8);
      #pragma unroll
      for (int c = 0; c < 4; ++c){
        short8_t b = *(const short8_t*)(bb + ((cb4+c)*16+l15)*72 + h*32 + kq8);
        acc[c] = MFMA16(a, b, acc[c]);
      }
    }
  }
  #pragma unroll
  for (int c = 0; c < 4; ++c){
    int jl = (cb4+c)*16 + l15;
    #pragma unroll
    for (int r = 0; r < 4; ++r){
      int row = row0 + rt*16 + rq + r;
      float v = acc[c][r];
      if (bn == 0) cneg[(size_t)row*H_ + jl] = 2.0f*(cb[jl] - v);
      else         h1pre[(size_t)row*H_ + jl] = v + q0[jl];
    }
  }
}

// ---------------- 128-dim Langevin: yc state in f32 MFMA accumulators ----------------
__global__ __launch_bounds__(512) void k_lv2(
    const ushort* __restrict__ M2bf, const ushort* __restrict__ GGr,
    const float* __restrict__ y0c0, const ushort* __restrict__ NWR,
    const float* __restrict__ b1, const float* __restrict__ r0v,
    const float* __restrict__ cneg,
    ushort* __restrict__ hfin_bf, float* __restrict__ capre){
  __shared__ __align__(16) ushort abuf[16*136];
  __shared__ __align__(16) ushort glbuf[16*136];
  const int t = threadIdx.x, lane = t & 63, w = t >> 6;
  const int l15 = lane & 15, kq8 = (lane >> 4)*8, rq = (lane >> 4)*4;
  const int b0 = blockIdx.x * 16;
  const int myc = w*16 + l15;
  const int col2 = w*32 + l15;

  f32x4_t acc[2];
  #pragma unroll
  for (int nf = 0; nf < 2; ++nf)
    #pragma unroll
    for (int r = 0; r < 4; ++r)
      acc[nf][r] = y0c0[(size_t)(b0+rq+r)*256 + col2 + nf*16];
  float cn[4];
  #pragma unroll
  for (int r = 0; r < 4; ++r) cn[r] = cneg[(size_t)(b0+rq+r)*H_ + myc];
  float bb2[2];
  bb2[0] = (w < 4) ? b1[col2] : 0.0f;
  bb2[1] = (w < 4) ? b1[col2+16] : 0.0f;
  ushort nx[8];
  #pragma unroll
  for (int nf = 0; nf < 2; ++nf)
    #pragma unroll
    for (int r = 0; r < 4; ++r)
      nx[nf*4+r] = NWR[(size_t)(b0+rq+r)*256 + col2 + nf*16];

  #pragma unroll 1
  for (int s = 0; s < 10; ++s){
    if (w < 4){
      #pragma unroll
      for (int nf = 0; nf < 2; ++nf)
        #pragma unroll
        for (int r = 0; r < 4; ++r)
          abuf[(rq+r)*136 + col2 + nf*16] = f2bf(fmaxf(acc[nf][r] + bb2[nf], 0.0f));
    }
    __syncthreads();
    f32x4_t g2 = {};
    #pragma unroll
    for (int h = 0; h < 4; ++h){
      short8_t a = *(const short8_t*)&abuf[l15*136 + h*32 + kq8];
      short8_t b = *(const short8_t*)&M2bf[(size_t)myc*H_ + h*32 + kq8];
      g2 = MFMA16(a, b, g2);
    }
    #pragma unroll
    for (int r = 0; r < 4; ++r){
      float g = (abuf[(rq+r)*136 + myc] != 0) ? (g2[r] + cn[r]) : 0.0f;
      glbuf[(rq+r)*136 + myc] = f2bf(g);
    }
    __syncthreads();
    #pragma unroll
    for (int nf = 0; nf < 2; ++nf)
      #pragma unroll
      for (int h = 0; h < 4; ++h){
        short8_t a = *(const short8_t*)&glbuf[l15*136 + h*32 + kq8];
        short8_t b = *(const short8_t*)&GGr[(size_t)(col2 + nf*16)*H_ + h*32 + kq8];
        acc[nf] = MFMA16(a, b, acc[nf]);
      }
    #pragma unroll
    for (int nf = 0; nf < 2; ++nf)
      #pragma unroll
      for (int r = 0; r < 4; ++r)
        acc[nf][r] += bf2f(nx[nf*4+r]);
    if (s < 9){
      #pragma unroll
      for (int nf = 0; nf < 2; ++nf)
        #pragma unroll
        for (int r = 0; r < 4; ++r)
          nx[nf*4+r] = NWR[(size_t)(s+1)*2097152 + (size_t)(b0+rq+r)*256 + col2 + nf*16];
    }
    __syncthreads();
  }
  if (w < 4){
    #pragma unroll
    for (int nf = 0; nf < 2; ++nf)
      #pragma unroll
      for (int r = 0; r < 4; ++r)
        hfin_bf[(size_t)(b0+rq+r)*H_ + col2 + nf*16] = f2bf(fmaxf(acc[nf][r] + bb2[nf], 0.0f));
  } else {
    #pragma unroll
    for (int nf = 0; nf < 2; ++nf)
      #pragma unroll
      for (int r = 0; r < 4; ++r)
        capre[(size_t)(b0+rq+r)*H_ + (col2 + nf*16 - 128)] = acc[nf][r] + r0v[col2 + nf*16 - 128];
  }
}

// ---------------- x_recon (MFMA): out = hfin @ W2^T + b2 ----------------
__global__ __launch_bounds__(256) void k_xrecon_mfma(
    const ushort* __restrict__ hfin_bf, const ushort* __restrict__ W2bf,
    const float* __restrict__ b2, float* __restrict__ out){
  __shared__ __align__(16) ushort at[64*136];
  __shared__ __align__(16) ushort bt[128*136];
  const int tid = threadIdx.x, lane = tid & 63, w = tid >> 6;
  const int bm = blockIdx.x >> 5, bn = blockIdx.x & 31;
  const int row0 = bm*64, c0 = bn*128;
  const int l15 = lane & 15, kq8 = (lane >> 4)*8, rq = (lane >> 4)*4;
  { int r = tid >> 2, kq = (tid & 3)*32;
    const ushort* src = &hfin_bf[(size_t)(row0 + r)*H_ + kq];
    #pragma unroll
    for (int i = 0; i < 4; ++i) *(uint4*)&at[r*136 + kq + 8*i] = *(const uint4*)(src + 8*i);
  }
  { int n = tid >> 1, kh = (tid & 1)*64;
    const ushort* src = &W2bf[(size_t)(c0 + n)*H_ + kh];
    #pragma unroll
    for (int i = 0; i < 8; ++i) *(uint4*)&bt[n*136 + kh + 8*i] = *(const uint4*)(src + 8*i);
  }
  __syncthreads();
  f32x4_t acc[8] = {};
  #pragma unroll
  for (int k = 0; k < 4; ++k){
    short8_t a = *(const short8_t*)&at[(w*16 + l15)*136 + k*32 + kq8];
    #pragma unroll
    for (int nf = 0; nf < 8; ++nf){
      short8_t b = *(const short8_t*)&bt[(nf*16 + l15)*136 + k*32 + kq8];
      acc[nf] = MFMA16(a, b, acc[nf]);
    }
  }
  #pragma unroll
  for (int nf = 0; nf < 8; ++nf){
    int c = c0 + nf*16 + l15;
    float bbv = b2[c];
    #pragma unroll
    for (int r = 0; r < 4; ++r){
      int row = row0 + w*16 + rq + r;
      out[(size_t)row*XD_ + c] = acc[nf][r] + bbv;
    }
  }
}

// ---------------- per-row transformer tail -> y_pred ----------------
__device__ __forceinline__ float wsum64(float v){
  #pragma unroll
  for (int off = 32; off > 0; off >>= 1) v += __shfl_xor(v, off, 64);
  return v;
}

__global__ __launch_bounds__(256) void k_tail(
    const float* __restrict__ h1pre, const float* __restrict__ capre,
    const float* __restrict__ ln1g, const float* __restrict__ ln1b,
    const float* __restrict__ ln2g, const float* __restrict__ ln2b,
    const float* __restrict__ ln3g, const float* __restrict__ ln3b,
    const float* __restrict__ fW1, const float* __restrict__ fb1,
    const float* __restrict__ fW2, const float* __restrict__ fb2,
    const float* __restrict__ outW, const float* __restrict__ outb,
    float* __restrict__ y){
  __shared__ float sh2[4][128];
  __shared__ float st1[4][128];
  const int tid = threadIdx.x;
  const int w = tid >> 6;
  const int l = tid & 63;
  const int b = blockIdx.x * 4 + w;
  const float* hp = h1pre + (size_t)b * H_;
  const float* cp = capre + (size_t)b * H_;
  float x0 = hp[l], x1 = hp[l+64];
  float m = wsum64(x0 + x1) * (1.0f/128.0f);
  float d0 = x0 - m, d1 = x1 - m;
  float v = wsum64(d0*d0 + d1*d1) * (1.0f/128.0f);
  float rs = rsqrtf(v + 1e-5f);
  float h1a = d0 * rs * ln1g[l]    + ln1b[l];
  float h1b = d1 * rs * ln1g[l+64] + ln1b[l+64];
  x0 = h1a + cp[l]; x1 = h1b + cp[l+64];
  m = wsum64(x0 + x1) * (1.0f/128.0f);
  d0 = x0 - m; d1 = x1 - m;
  v = wsum64(d0*d0 + d1*d1) * (1.0f/128.0f);
  rs = rsqrtf(v + 1e-5f);
  float h2a = d0 * rs * ln2g[l]    + ln2b[l];
  float h2b = d1 * rs * ln2g[l+64] + ln2b[l+64];
  sh2[w][l] = h2a; sh2[w][l+64] = h2b;
  __syncthreads();
  float ta = fb1[l], tb = fb1[l+64];
  #pragma unroll 8
  for (int m4 = 0; m4 < H_; m4 += 4){
    float4 hv = *(const float4*)&sh2[w][m4];
    float4 wa = *(const float4*)&fW1[(size_t)l*H_ + m4];
    float4 wb = *(const float4*)&fW1[(size_t)(l+64)*H_ + m4];
    ta = fmaf(wa.x, hv.x, ta); ta = fmaf(wa.y, hv.y, ta); ta = fmaf(wa.z, hv.z, ta); ta = fmaf(wa.w, hv.w, ta);
    tb = fmaf(wb.x, hv.x, tb); tb = fmaf(wb.y, hv.y, tb); tb = fmaf(wb.z, hv.z, tb); tb = fmaf(wb.w, hv.w, tb);
  }
  ta = fmaxf(ta, 0.0f); tb = fmaxf(tb, 0.0f);
  st1[w][l] = ta; st1[w][l+64] = tb;
  __syncthreads();
  float fa = fb2[l], fbv = fb2[l+64];
  #pragma unroll 8
  for (int m4 = 0; m4 < H_; m4 += 4){
    float4 tv = *(const float4*)&st1[w][m4];
    float4 wa = *(const float4*)&fW2[(size_t)l*H_ + m4];
    float4 wb = *(const float4*)&fW2[(size_t)(l+64)*H_ + m4];
    fa  = fmaf(wa.x, tv.x, fa);  fa  = fmaf(wa.y, tv.y, fa);  fa  = fmaf(wa.z, tv.z, fa);  fa  = fmaf(wa.w, tv.w, fa);
    fbv = fmaf(wb.x, tv.x, fbv); fbv = fmaf(wb.y, tv.y, fbv); fbv = fmaf(wb.z, tv.z, fbv); fbv = fmaf(wb.w, tv.w, fbv);
  }
  x0 = h2a + fa; x1 = h2b + fbv;
  m = wsum64(x0 + x1) * (1.0f/128.0f);
  d0 = x0 - m; d1 = x1 - m;
  v = wsum64(d0*d0 + d1*d1) * (1.0f/128.0f);
  rs = rsqrtf(v + 1e-5f);
  float h3a = d0 * rs * ln3g[l]    + ln3b[l];
  float h3b = d1 * rs * ln3g[l+64] + ln3b[l+64];
  float py = wsum64(outW[l]*h3a + outW[l+64]*h3b);
  if (l == 0) y[b] = py + outb[0];
}

// ---------------- host ----------------
extern "C" void kernel_launch(void* const* d_in, const int* in_sizes, int n_in,
                              void* d_out, int out_size, void* d_ws, size_t ws_size,
                              hipStream_t stream){
  const float* x      = (const float*)d_in[0];
  const float* pxW1   = (const float*)d_in[1];
  const float* pxb1   = (const float*)d_in[2];
  const float* pxW2   = (const float*)d_in[3];
  const float* pxb2   = (const float*)d_in[4];
  const float* embW   = (const float*)d_in[5];
  const float* embb   = (const float*)d_in[6];
  const float* xpW    = (const float*)d_in[7];
  const float* xpb    = (const float*)d_in[8];
  const float* zpW    = (const float*)d_in[9];
  const float* zpb    = (const float*)d_in[10];
  const float* saWqkv = (const float*)d_in[11];
  const float* sabqkv = (const float*)d_in[12];
  const float* saWo   = (const float*)d_in[13];
  const float* sabo   = (const float*)d_in[14];
  const float* caWqkv = (const float*)d_in[15];
  const float* cabqkv = (const float*)d_in[16];
  const float* caWo   = (const float*)d_in[17];
  const float* cabo   = (const float*)d_in[18];
  const float* fW1    = (const float*)d_in[19];
  const float* fb1    = (const float*)d_in[20];
  const float* fW2    = (const float*)d_in[21];
  const float* fb2    = (const float*)d_in[22];
  const float* ln1g   = (const float*)d_in[23];
  const float* ln1b   = (const float*)d_in[24];
  const float* ln2g   = (const float*)d_in[25];
  const float* ln2b   = (const float*)d_in[26];
  const float* ln3g   = (const float*)d_in[27];
  const float* ln3b   = (const float*)d_in[28];
  const float* outW   = (const float*)d_in[29];
  const float* outb   = (const float*)d_in[30];
  (void)in_sizes; (void)n_in; (void)out_size; (void)ws_size;

  float* ws    = (float*)d_ws;
  float* cneg  = ws;                          // 1048576
  float* h1pre = cneg + (size_t)B_*H_;        // 1048576
  float* capre = h1pre + (size_t)B_*H_;       // 1048576
  float* Rm    = capre + (size_t)B_*H_;       // 131072
  float* Sm    = Rm + (size_t)H_*ZD_;         // 16384
  float* Um    = Sm + H_*H_;                  // 16384
  float* Tm    = Um + H_*H_;                  // 8192
  float* vs0   = Tm + H_*XE_;
  float* vu0   = vs0 + H_;
  float* vt0   = vu0 + H_;
  float* vq0   = vt0 + H_;
  float* vr0   = vq0 + H_;
  float* vcb   = vr0 + H_;
  float* Mpart = vcb + H_;                    // 131072
  float* Gpart = Mpart + 131072;              // 262144
  uint32_t* dkeys = (uint32_t*)(Gpart + 262144);  // 32 u32
  float* y0c0  = (float*)(dkeys + 32);        // 2097152 f32
  ushort* WXT   = (ushort*)(y0c0 + (size_t)B_*256);  // 1048576
  ushort* W2bf  = WXT + (size_t)256*XD_;      // 524288
  ushort* Mbf   = W2bf + (size_t)XD_*H_;      // 16384 (=2M)
  ushort* FBT   = Mbf + H_*H_;                // 262144
  ushort* GGr   = FBT + (size_t)256*ZD_;      // 32768
  ushort* hfin  = GGr + (size_t)256*H_;       // 1048576
  ushort* NWR   = hfin + (size_t)B_*H_;       // 20971520 (10 x 8192 x 256)

  float* xre   = (float*)d_out;
  float* ypred = xre + (size_t)B_*XD_;

  k_prepA   <<<512,  64, 0, stream>>>(saWo, saWqkv, caWo, caWqkv, Sm, Um);
  k_prepB   <<<6,    64, 0, stream>>>(saWo, sabqkv, sabo, caWo, cabqkv, cabo, pxW2, pxb2,
                                      vs0, vu0, vcb, dkeys);
  k_prepTR  <<<2180, 64, 0, stream>>>(Sm, Um, xpW, zpW, xpb, zpb, vs0, vu0, Tm, Rm, vt0, vr0);
  k_prepMG_part <<<1536, 256, 0, stream>>>(pxW2, pxW1, Rm, Mpart, Gpart);
  k_prepWXT <<<4096, 256, 0, stream>>>(pxW2, Tm, embW, embb, vt0, WXT, vq0);
  k_conv    <<<3264, 256, 0, stream>>>(pxW2, pxW1, Rm, Mpart, Gpart, W2bf, Mbf, FBT, GGr);
  k_noiseproj <<<1408, 256, 0, stream>>>(FBT, dkeys, y0c0, NWR);
  k_xpass_mfma <<<512, 256, 0, stream>>>(x, WXT, vcb, vq0, cneg, h1pre);
  k_lv2     <<<512, 512, 0, stream>>>(Mbf, GGr, y0c0, NWR, pxb1, vr0, cneg, hfin, capre);
  k_xrecon_mfma <<<4096, 256, 0, stream>>>(hfin, W2bf, pxb2, xre);
  k_tail    <<<2048, 256, 0, stream>>>(h1pre, capre, ln1g, ln1b, ln2g, ln2b, ln3g, ln3b,
                                       fW1, fb1, fW2, fb2, outW, outb, ypred);
}

// Round 13
// 874.304 us; speedup vs baseline: 1.0925x; 1.0676x over previous
//
#include <hip/hip_runtime.h>
#include <hip/hip_bf16.h>
#include <cstdint>
#include <cstddef>
#include <cmath>

#define B_     8192
#define XD_    4096
#define ZD_    1024
#define XE_    64
#define H_     128
#define ZN_    (B_*ZD_)

typedef __attribute__((ext_vector_type(8))) short short8_t;   // 8 x bf16 (4 VGPR)
typedef __attribute__((ext_vector_type(4))) float f32x4_t;    // MFMA accumulator
#define MFMA16(a,b,c) __builtin_amdgcn_mfma_f32_16x16x32_bf16((a),(b),(c),0,0,0)

// ---------------- threefry2x32 (bit-exact vs JAX, partitionable mode — validated R1-R12) ----
__host__ __device__ __forceinline__ uint32_t rotl32_(uint32_t x, int r){
#ifdef __HIP_DEVICE_COMPILE__
  return __builtin_rotateleft32(x, (uint32_t)r);
#else
  return (x<<r)|(x>>(32-r));
#endif
}

__host__ __device__ __forceinline__ void tf2x32(uint32_t k0, uint32_t k1,
                                                uint32_t x0, uint32_t x1,
                                                uint32_t* o0, uint32_t* o1){
  uint32_t k2 = k0 ^ k1 ^ 0x1BD11BDAu;
  x0 += k0; x1 += k1;
  x0 += x1; x1 = rotl32_(x1,13); x1 ^= x0;
  x0 += x1; x1 = rotl32_(x1,15); x1 ^= x0;
  x0 += x1; x1 = rotl32_(x1,26); x1 ^= x0;
  x0 += x1; x1 = rotl32_(x1, 6); x1 ^= x0;
  x0 += k1; x1 += k2 + 1u;
  x0 += x1; x1 = rotl32_(x1,17); x1 ^= x0;
  x0 += x1; x1 = rotl32_(x1,29); x1 ^= x0;
  x0 += x1; x1 = rotl32_(x1,16); x1 ^= x0;
  x0 += x1; x1 = rotl32_(x1,24); x1 ^= x0;
  x0 += k2; x1 += k0 + 2u;
  x0 += x1; x1 = rotl32_(x1,13); x1 ^= x0;
  x0 += x1; x1 = rotl32_(x1,15); x1 ^= x0;
  x0 += x1; x1 = rotl32_(x1,26); x1 ^= x0;
  x0 += x1; x1 = rotl32_(x1, 6); x1 ^= x0;
  x0 += k0; x1 += k1 + 3u;
  x0 += x1; x1 = rotl32_(x1,17); x1 ^= x0;
  x0 += x1; x1 = rotl32_(x1,29); x1 ^= x0;
  x0 += x1; x1 = rotl32_(x1,16); x1 ^= x0;
  x0 += x1; x1 = rotl32_(x1,24); x1 ^= x0;
  x0 += k1; x1 += k2 + 4u;
  x0 += x1; x1 = rotl32_(x1,13); x1 ^= x0;
  x0 += x1; x1 = rotl32_(x1,15); x1 ^= x0;
  x0 += x1; x1 = rotl32_(x1,26); x1 ^= x0;
  x0 += x1; x1 = rotl32_(x1, 6); x1 ^= x0;
  x0 += k2; x1 += k0 + 5u;
  *o0 = x0; *o1 = x1;
}

// XLA ErfInv32; fast v_log (validated R8-R12, absmax unchanged)
__device__ __forceinline__ float erfinv_(float x){
  float w = -__logf(fmaf(-x, x, 1.0f));
  float p;
  if (w < 5.0f){
    w -= 2.5f;
    p = 2.81022636e-08f;
    p = fmaf(p, w, 3.43273939e-07f);
    p = fmaf(p, w, -3.5233877e-06f);
    p = fmaf(p, w, -4.39150654e-06f);
    p = fmaf(p, w, 0.00021858087f);
    p = fmaf(p, w, -0.00125372503f);
    p = fmaf(p, w, -0.00417768164f);
    p = fmaf(p, w, 0.246640727f);
    p = fmaf(p, w, 1.50140941f);
  } else {
    w = sqrtf(w) - 3.0f;
    p = -0.000200214257f;
    p = fmaf(p, w, 0.000100950558f);
    p = fmaf(p, w, 0.00134934322f);
    p = fmaf(p, w, -0.00367342844f);
    p = fmaf(p, w, 0.00573950773f);
    p = fmaf(p, w, -0.0076224613f);
    p = fmaf(p, w, 0.00943887047f);
    p = fmaf(p, w, 1.00167406f);
    p = fmaf(p, w, 2.83297682f);
  }
  return p * x;
}

__device__ __forceinline__ float bits_to_normal(uint32_t bits){
  float f = __uint_as_float((bits >> 9) | 0x3f800000u) - 1.0f;
  float u = fmaxf(-0.99999994f, fmaf(f, 2.0f, -0.99999994f));
  return 1.41421356f * erfinv_(u);
}

__device__ __forceinline__ float rng_normal(uint32_t k0, uint32_t k1, uint32_t idx){
  uint32_t o0, o1; tf2x32(k0, k1, 0u, idx, &o0, &o1);
  return bits_to_normal(o0 ^ o1);
}

__device__ __forceinline__ ushort f2bf(float f){
  return __builtin_bit_cast(ushort, __float2bfloat16(f));
}
__device__ __forceinline__ float bf2f(ushort u){ return __uint_as_float(((uint32_t)u) << 16); }

// 8 bf16 normals (counters base..base+7) into a uint4 (registers)
__device__ __forceinline__ void gen8(uint32_t k0, uint32_t k1, uint32_t base, uint4* g){
  union { ushort u[8]; uint4 q; } pk;
  #pragma unroll
  for (int j = 0; j < 8; ++j) pk.u[j] = f2bf(rng_normal(k0,k1,base+(uint32_t)j));
  *g = pk.q;
}

// ---------------- weight-prep kernels (f32) ----------------
__global__ void k_prepA(const float* __restrict__ saWo, const float* __restrict__ saWqkv,
                        const float* __restrict__ caWo, const float* __restrict__ caWqkv,
                        float* __restrict__ S, float* __restrict__ U){
  int blk = blockIdx.x, tid = threadIdx.x;
  int idx = (blk & 255) * 64 + tid;
  int i = idx >> 7, j = idx & 127;
  if (blk < 256){
    float acc = (i == j) ? 1.0f : 0.0f;
    for (int k = 0; k < H_; ++k) acc += saWo[i*H_ + k] * saWqkv[(2*H_ + k)*H_ + j];
    S[idx] = acc;
  } else {
    float acc = 0.0f;
    for (int k = 0; k < H_; ++k) acc += caWo[i*H_ + k] * caWqkv[(2*H_ + k)*H_ + j];
    U[idx] = acc;
  }
}

__global__ void k_prepB(const float* __restrict__ saWo, const float* __restrict__ sabqkv, const float* __restrict__ sabo,
                        const float* __restrict__ caWo, const float* __restrict__ cabqkv, const float* __restrict__ cabo,
                        const float* __restrict__ W2, const float* __restrict__ pb2,
                        float* __restrict__ s0, float* __restrict__ u0, float* __restrict__ cb,
                        uint32_t* __restrict__ dkeys){
  int blk = blockIdx.x, tid = threadIdx.x;
  if (blk == 0 && tid == 0){
    for (uint32_t i = 0; i < 11; ++i){
      uint32_t a, b; tf2x32(0u, 42u, 0u, i, &a, &b);
      dkeys[2*i] = a; dkeys[2*i+1] = b;
    }
  }
  if (blk < 2){
    int i = blk*64 + tid;
    float acc = sabo[i];
    for (int k = 0; k < H_; ++k) acc += saWo[i*H_ + k] * sabqkv[2*H_ + k];
    s0[i] = acc;
  } else if (blk < 4){
    int i = (blk-2)*64 + tid;
    float acc = cabo[i];
    for (int k = 0; k < H_; ++k) acc += caWo[i*H_ + k] * cabqkv[2*H_ + k];
    u0[i] = acc;
  } else {
    int j = (blk-4)*64 + tid;
    float acc = 0.0f;
    for (int c = 0; c < XD_; ++c) acc += pb2[c] * W2[(size_t)c*H_ + j];
    cb[j] = acc;
  }
}

__global__ void k_prepTR(const float* __restrict__ S, const float* __restrict__ U,
                         const float* __restrict__ xpW, const float* __restrict__ zpW,
                         const float* __restrict__ xpb, const float* __restrict__ zpb,
                         const float* __restrict__ s0, const float* __restrict__ u0,
                         float* __restrict__ T, float* __restrict__ R,
                         float* __restrict__ t0, float* __restrict__ r0v){
  int blk = blockIdx.x, tid = threadIdx.x;
  if (blk < 128){
    int idx = blk*64 + tid;
    int i = idx >> 6, e = idx & 63;
    float acc = 0.0f;
    for (int m = 0; m < H_; ++m) acc += S[i*H_ + m] * xpW[m*XE_ + e];
    T[idx] = acc;
  } else if (blk < 2176){
    int idx = (blk-128)*64 + tid;
    int i = idx >> 10, k = idx & 1023;
    float acc = 0.0f;
    for (int m = 0; m < H_; ++m) acc += U[i*H_ + m] * zpW[(size_t)m*ZD_ + k];
    R[idx] = acc;
  } else if (blk < 2178){
    int i = (blk-2176)*64 + tid;
    float acc = s0[i];
    for (int m = 0; m < H_; ++m) acc += S[i*H_ + m] * xpb[m];
    t0[i] = acc;
  } else {
    int i = (blk-2178)*64 + tid;
    float acc = u0[i];
    for (int m = 0; m < H_; ++m) acc += U[i*H_ + m] * zpb[m];
    r0v[i] = acc;
  }
}

// split-K=8 partials for M = W2^T W2 (K=4096) and G/Gr (K=1024). Fold in k_conv.
__global__ void k_prepMG_part(const float* __restrict__ W2, const float* __restrict__ W1,
                              const float* __restrict__ R,
                              float* __restrict__ Mpart, float* __restrict__ Gpart){
  int gid = blockIdx.x*256 + threadIdx.x;   // 393216
  if (gid < 131072){
    int slice = gid >> 14, i = gid & 16383;
    int j1 = i >> 7, j2 = i & 127;
    int c0 = slice*512;
    float acc = 0.0f;
    for (int c = c0; c < c0+512; ++c)
      acc += W2[(size_t)c*H_ + j1] * W2[(size_t)c*H_ + j2];
    Mpart[(size_t)slice*16384 + i] = acc;
  } else {
    int g = gid - 131072;
    int slice = g >> 15, i2 = g & 32767;
    int i = i2 >> 7, k = i2 & 127;
    int m0 = slice*128;
    float acc = 0.0f;
    if (i < 128){
      for (int m = m0; m < m0+128; ++m)
        acc += W1[(size_t)i*ZD_ + m] * W1[(size_t)k*ZD_ + m];
    } else {
      for (int m = m0; m < m0+128; ++m)
        acc += W1[(size_t)k*ZD_ + m] * R[(size_t)(i-128)*ZD_ + m];
    }
    Gpart[(size_t)slice*32768 + i2] = acc;
  }
}

__global__ void k_prepWXT(const float* __restrict__ W2, const float* __restrict__ T,
                          const float* __restrict__ embW, const float* __restrict__ embb,
                          const float* __restrict__ t0,
                          ushort* __restrict__ WXT, float* __restrict__ q0){
  int idx = blockIdx.x*256 + threadIdx.x;   // 1048576
  int j = idx >> 12, c = idx & 4095;
  float v;
  if (j < H_) v = W2[(size_t)c*H_ + j];
  else {
    int i = j - H_;
    float acc = 0.0f;
    for (int e = 0; e < XE_; ++e) acc += T[i*XE_ + e] * embW[(size_t)e*XD_ + c];
    v = acc;
  }
  WXT[idx] = f2bf(v);
  if (idx < H_){
    float acc = t0[idx];
    for (int e = 0; e < XE_; ++e) acc += T[idx*XE_ + e] * embb[e];
    q0[idx] = acc;
  }
}

// W2bf[524288]; Mbf = f2bf(2*sum Mpart) [16384]; FBT=[W1;R] [262144]; GGr = f2bf(-0.005*sum Gpart) [32768]
__global__ void k_conv(const float* __restrict__ W2, const float* __restrict__ W1,
                       const float* __restrict__ R,
                       const float* __restrict__ Mpart, const float* __restrict__ Gpart,
                       ushort* __restrict__ W2bf, ushort* __restrict__ Mbf,
                       ushort* __restrict__ FBT, ushort* __restrict__ GGr){
  int idx = blockIdx.x*256 + threadIdx.x;   // 835584
  if (idx < 524288) W2bf[idx] = f2bf(W2[idx]);
  else if (idx < 540672){
    int i = idx - 524288;
    float s = 0.0f;
    #pragma unroll
    for (int p = 0; p < 8; ++p) s += Mpart[(size_t)p*16384 + i];
    Mbf[i] = f2bf(2.0f*s);
  } else if (idx < 802816){
    int i = idx - 540672; int j = i >> 10, k = i & 1023;
    FBT[i] = f2bf(j < H_ ? W1[j*ZD_ + k] : R[(size_t)(j-H_)*ZD_ + k]);
  } else {
    int i = idx - 802816;
    float s = 0.0f;
    #pragma unroll
    for (int p = 0; p < 8; ++p) s += Gpart[(size_t)p*32768 + i];
    GGr[i] = f2bf(-0.005f*s);
  }
}

// ---------------- noise projection: pass p rows [8192][1024] RNG @ FBT^T -> [8192][256]
// R12 post-mortem: VALU-issue time is invariantly ~260us across structures (the
// RNG chain's empirical cost), but kernel ran 440us at VALU 59% — in-order waves
// issued load->mfma 32x/iter, each s_waitcnt exposing ~200cy L2 latency with only
// ~2.4 waves/SIMD to cover. Fix: hoist each half-iter's 16 B-loads ABOVE its gen8
// (sched_barrier(0) pins them) so the ~400cy RNG VALU chain covers the L2 latency
// in-wave; MFMAs then run from registers. br[16]=64 VGPR; ~105 arch VGPR total.
__global__ __launch_bounds__(256) void k_noiseproj(
    const ushort* __restrict__ FBT, const uint32_t* __restrict__ dkeys,
    float* __restrict__ y0c0, ushort* __restrict__ NWR){
  const int t = threadIdx.x, lane = t & 63, w = t >> 6;
  const int l15 = lane & 15, kq8 = (lane >> 4)*8, rq = (lane >> 4)*4;
  const int gwid = blockIdx.x*4 + w;         // 0..5631
  const int p = gwid >> 9, mb = gwid & 511;  // 11 passes x 512 row-tiles of 16
  const int row0 = mb*16;
  const uint32_t k0 = dkeys[2*p], k1 = dkeys[2*p+1];
  const uint32_t rbase = (uint32_t)(row0 + l15)*1024u + (uint32_t)kq8;
  f32x4_t acc[16] = {};
  #pragma unroll 1
  for (int it = 0; it < 16; ++it){
    const ushort* fb = &FBT[(size_t)l15*ZD_ + it*64 + kq8];
    uint4 br[16];
    // ---- h=0: issue all 16 B loads first, pin, then RNG covers their latency
    #pragma unroll
    for (int cf = 0; cf < 16; ++cf) br[cf] = *(const uint4*)(fb + (size_t)cf*16*ZD_);
    __builtin_amdgcn_sched_barrier(0);
    uint4 g0; gen8(k0, k1, rbase + (uint32_t)(it*64), &g0);
    short8_t a0 = __builtin_bit_cast(short8_t, g0);
    #pragma unroll
    for (int cf = 0; cf < 16; ++cf)
      acc[cf] = MFMA16(a0, __builtin_bit_cast(short8_t, br[cf]), acc[cf]);
    // ---- h=1
    #pragma unroll
    for (int cf = 0; cf < 16; ++cf) br[cf] = *(const uint4*)(fb + (size_t)cf*16*ZD_ + 32);
    __builtin_amdgcn_sched_barrier(0);
    uint4 g1; gen8(k0, k1, rbase + (uint32_t)(it*64 + 32), &g1);
    short8_t a1 = __builtin_bit_cast(short8_t, g1);
    #pragma unroll
    for (int cf = 0; cf < 16; ++cf)
      acc[cf] = MFMA16(a1, __builtin_bit_cast(short8_t, br[cf]), acc[cf]);
  }
  #pragma unroll
  for (int cf = 0; cf < 16; ++cf){
    int col = cf*16 + l15;
    #pragma unroll
    for (int r = 0; r < 4; ++r){
      int row = row0 + rq + r;
      float v = acc[cf][r];
      if (p == 0) y0c0[(size_t)row*256 + col] = v;
      else NWR[(size_t)(p-1)*2097152 + (size_t)row*256 + col] = f2bf(0.1f*v);
    }
  }
}

// ---------------- x-pass (MFMA, dbuf, 1 barrier/iter): [cneg | h1pre] = x @ WXT^T ----
// BM=32, BN=128, grid 512, 256 thr. Carried-register prefetch (R8-proven).
__global__ __launch_bounds__(256) void k_xpass_mfma(
    const float* __restrict__ x, const ushort* __restrict__ WXT,
    const float* __restrict__ cb, const float* __restrict__ q0,
    float* __restrict__ cneg, float* __restrict__ h1pre){
  __shared__ __align__(16) ushort xt[2][32*72];
  __shared__ __align__(16) ushort bt[2][128*72];
  const int t = threadIdx.x, lane = t & 63, w = t >> 6;
  const int bm = blockIdx.x >> 1, bn = blockIdx.x & 1;
  const int row0 = bm*32, ncol0 = bn*128;
  const int l15 = lane & 15, kq8 = (lane >> 4)*8, rq = (lane >> 4)*4;
  const int rt = w & 1, cb4 = (w >> 1)*4;
  const int xr = t >> 3, xk = (t & 7)*8;
  const int wn = t >> 1, wk = (t & 1)*32;
  f32x4_t acc[4] = {};
  {
    float4 v0 = *(const float4*)&x[(size_t)(row0+xr)*XD_ + xk];
    float4 v1 = *(const float4*)&x[(size_t)(row0+xr)*XD_ + xk + 4];
    union { ushort u[8]; uint4 q; } p;
    p.u[0]=f2bf(v0.x); p.u[1]=f2bf(v0.y); p.u[2]=f2bf(v0.z); p.u[3]=f2bf(v0.w);
    p.u[4]=f2bf(v1.x); p.u[5]=f2bf(v1.y); p.u[6]=f2bf(v1.z); p.u[7]=f2bf(v1.w);
    *(uint4*)&xt[0][xr*72 + xk] = p.q;
    const ushort* s = &WXT[(size_t)(ncol0+wn)*XD_ + wk];
    uint4 b0v=*(const uint4*)s, b1v=*(const uint4*)(s+8), b2v=*(const uint4*)(s+16), b3v=*(const uint4*)(s+24);
    ushort* d = &bt[0][wn*72 + wk];
    *(uint4*)d=b0v; *(uint4*)(d+8)=b1v; *(uint4*)(d+16)=b2v; *(uint4*)(d+24)=b3v;
  }
  float4 xv0, xv1; uint4 wb0, wb1, wb2, wb3;
  {
    xv0 = *(const float4*)&x[(size_t)(row0+xr)*XD_ + 64 + xk];
    xv1 = *(const float4*)&x[(size_t)(row0+xr)*XD_ + 64 + xk + 4];
    const ushort* s = &WXT[(size_t)(ncol0+wn)*XD_ + 64 + wk];
    wb0=*(const uint4*)s; wb1=*(const uint4*)(s+8); wb2=*(const uint4*)(s+16); wb3=*(const uint4*)(s+24);
  }
  #pragma unroll 1
  for (int it = 0; it < 64; ++it){
    __syncthreads();
    if (it < 63){
      union { ushort u[8]; uint4 q; } p;
      p.u[0]=f2bf(xv0.x); p.u[1]=f2bf(xv0.y); p.u[2]=f2bf(xv0.z); p.u[3]=f2bf(xv0.w);
      p.u[4]=f2bf(xv1.x); p.u[5]=f2bf(xv1.y); p.u[6]=f2bf(xv1.z); p.u[7]=f2bf(xv1.w);
      *(uint4*)&xt[(it+1)&1][xr*72 + xk] = p.q;
      ushort* d = &bt[(it+1)&1][wn*72 + wk];
      *(uint4*)d=wb0; *(uint4*)(d+8)=wb1; *(uint4*)(d+16)=wb2; *(uint4*)(d+24)=wb3;
    }
    if (it < 62){
      const int kt = (it+2)*64;
      xv0 = *(const float4*)&x[(size_t)(row0+xr)*XD_ + kt + xk];
      xv1 = *(const float4*)&x[(size_t)(row0+xr)*XD_ + kt + xk + 4];
      const ushort* s = &WXT[(size_t)(ncol0+wn)*XD_ + kt + wk];
      wb0=*(const uint4*)s; wb1=*(const uint4*)(s+8); wb2=*(const uint4*)(s+16); wb3=*(const uint4*)(s+24);
    }
    const ushort* xb = &xt[it&1][(rt*16+l15)*72];
    const ushort* bb = &bt[it&1][0];
    #pragma unroll
    for (int h = 0; h < 2; ++h){
      short8_t a = *(const short8_t*)(xb + h*32 + kq8);
      #pragma unroll
      for (int c = 0; c < 4; ++c){
        short8_t b = *(const short8_t*)(bb + ((cb4+c)*16+l15)*72 + h*32 + kq8);
        acc[c] = MFMA16(a, b, acc[c]);
      }
    }
  }
  #pragma unroll
  for (int c = 0; c < 4; ++c){
    int jl = (cb4+c)*16 + l15;
    #pragma unroll
    for (int r = 0; r < 4; ++r){
      int row = row0 + rt*16 + rq + r;
      float v = acc[c][r];
      if (bn == 0) cneg[(size_t)row*H_ + jl] = 2.0f*(cb[jl] - v);
      else         h1pre[(size_t)row*H_ + jl] = v + q0[jl];
    }
  }
}

// ---------------- 128-dim Langevin: yc state in f32 MFMA accumulators ----------------
__global__ __launch_bounds__(512) void k_lv2(
    const ushort* __restrict__ M2bf, const ushort* __restrict__ GGr,
    const float* __restrict__ y0c0, const ushort* __restrict__ NWR,
    const float* __restrict__ b1, const float* __restrict__ r0v,
    const float* __restrict__ cneg,
    ushort* __restrict__ hfin_bf, float* __restrict__ capre){
  __shared__ __align__(16) ushort abuf[16*136];
  __shared__ __align__(16) ushort glbuf[16*136];
  const int t = threadIdx.x, lane = t & 63, w = t >> 6;
  const int l15 = lane & 15, kq8 = (lane >> 4)*8, rq = (lane >> 4)*4;
  const int b0 = blockIdx.x * 16;
  const int myc = w*16 + l15;
  const int col2 = w*32 + l15;

  f32x4_t acc[2];
  #pragma unroll
  for (int nf = 0; nf < 2; ++nf)
    #pragma unroll
    for (int r = 0; r < 4; ++r)
      acc[nf][r] = y0c0[(size_t)(b0+rq+r)*256 + col2 + nf*16];
  float cn[4];
  #pragma unroll
  for (int r = 0; r < 4; ++r) cn[r] = cneg[(size_t)(b0+rq+r)*H_ + myc];
  float bb2[2];
  bb2[0] = (w < 4) ? b1[col2] : 0.0f;
  bb2[1] = (w < 4) ? b1[col2+16] : 0.0f;
  ushort nx[8];
  #pragma unroll
  for (int nf = 0; nf < 2; ++nf)
    #pragma unroll
    for (int r = 0; r < 4; ++r)
      nx[nf*4+r] = NWR[(size_t)(b0+rq+r)*256 + col2 + nf*16];

  #pragma unroll 1
  for (int s = 0; s < 10; ++s){
    if (w < 4){
      #pragma unroll
      for (int nf = 0; nf < 2; ++nf)
        #pragma unroll
        for (int r = 0; r < 4; ++r)
          abuf[(rq+r)*136 + col2 + nf*16] = f2bf(fmaxf(acc[nf][r] + bb2[nf], 0.0f));
    }
    __syncthreads();
    f32x4_t g2 = {};
    #pragma unroll
    for (int h = 0; h < 4; ++h){
      short8_t a = *(const short8_t*)&abuf[l15*136 + h*32 + kq8];
      short8_t b = *(const short8_t*)&M2bf[(size_t)myc*H_ + h*32 + kq8];
      g2 = MFMA16(a, b, g2);
    }
    #pragma unroll
    for (int r = 0; r < 4; ++r){
      float g = (abuf[(rq+r)*136 + myc] != 0) ? (g2[r] + cn[r]) : 0.0f;
      glbuf[(rq+r)*136 + myc] = f2bf(g);
    }
    __syncthreads();
    #pragma unroll
    for (int nf = 0; nf < 2; ++nf)
      #pragma unroll
      for (int h = 0; h < 4; ++h){
        short8_t a = *(const short8_t*)&glbuf[l15*136 + h*32 + kq8];
        short8_t b = *(const short8_t*)&GGr[(size_t)(col2 + nf*16)*H_ + h*32 + kq8];
        acc[nf] = MFMA16(a, b, acc[nf]);
      }
    #pragma unroll
    for (int nf = 0; nf < 2; ++nf)
      #pragma unroll
      for (int r = 0; r < 4; ++r)
        acc[nf][r] += bf2f(nx[nf*4+r]);
    if (s < 9){
      #pragma unroll
      for (int nf = 0; nf < 2; ++nf)
        #pragma unroll
        for (int r = 0; r < 4; ++r)
          nx[nf*4+r] = NWR[(size_t)(s+1)*2097152 + (size_t)(b0+rq+r)*256 + col2 + nf*16];
    }
    __syncthreads();
  }
  if (w < 4){
    #pragma unroll
    for (int nf = 0; nf < 2; ++nf)
      #pragma unroll
      for (int r = 0; r < 4; ++r)
        hfin_bf[(size_t)(b0+rq+r)*H_ + col2 + nf*16] = f2bf(fmaxf(acc[nf][r] + bb2[nf], 0.0f));
  } else {
    #pragma unroll
    for (int nf = 0; nf < 2; ++nf)
      #pragma unroll
      for (int r = 0; r < 4; ++r)
        capre[(size_t)(b0+rq+r)*H_ + (col2 + nf*16 - 128)] = acc[nf][r] + r0v[col2 + nf*16 - 128];
  }
}

// ---------------- x_recon (MFMA): out = hfin @ W2^T + b2 ----------------
__global__ __launch_bounds__(256) void k_xrecon_mfma(
    const ushort* __restrict__ hfin_bf, const ushort* __restrict__ W2bf,
    const float* __restrict__ b2, float* __restrict__ out){
  __shared__ __align__(16) ushort at[64*136];
  __shared__ __align__(16) ushort bt[128*136];
  const int tid = threadIdx.x, lane = tid & 63, w = tid >> 6;
  const int bm = blockIdx.x >> 5, bn = blockIdx.x & 31;
  const int row0 = bm*64, c0 = bn*128;
  const int l15 = lane & 15, kq8 = (lane >> 4)*8, rq = (lane >> 4)*4;
  { int r = tid >> 2, kq = (tid & 3)*32;
    const ushort* src = &hfin_bf[(size_t)(row0 + r)*H_ + kq];
    #pragma unroll
    for (int i = 0; i < 4; ++i) *(uint4*)&at[r*136 + kq + 8*i] = *(const uint4*)(src + 8*i);
  }
  { int n = tid >> 1, kh = (tid & 1)*64;
    const ushort* src = &W2bf[(size_t)(c0 + n)*H_ + kh];
    #pragma unroll
    for (int i = 0; i < 8; ++i) *(uint4*)&bt[n*136 + kh + 8*i] = *(const uint4*)(src + 8*i);
  }
  __syncthreads();
  f32x4_t acc[8] = {};
  #pragma unroll
  for (int k = 0; k < 4; ++k){
    short8_t a = *(const short8_t*)&at[(w*16 + l15)*136 + k*32 + kq8];
    #pragma unroll
    for (int nf = 0; nf < 8; ++nf){
      short8_t b = *(const short8_t*)&bt[(nf*16 + l15)*136 + k*32 + kq8];
      acc[nf] = MFMA16(a, b, acc[nf]);
    }
  }
  #pragma unroll
  for (int nf = 0; nf < 8; ++nf){
    int c = c0 + nf*16 + l15;
    float bbv = b2[c];
    #pragma unroll
    for (int r = 0; r < 4; ++r){
      int row = row0 + w*16 + rq + r;
      out[(size_t)row*XD_ + c] = acc[nf][r] + bbv;
    }
  }
}

// ---------------- per-row transformer tail -> y_pred ----------------
__device__ __forceinline__ float wsum64(float v){
  #pragma unroll
  for (int off = 32; off > 0; off >>= 1) v += __shfl_xor(v, off, 64);
  return v;
}

__global__ __launch_bounds__(256) void k_tail(
    const float* __restrict__ h1pre, const float* __restrict__ capre,
    const float* __restrict__ ln1g, const float* __restrict__ ln1b,
    const float* __restrict__ ln2g, const float* __restrict__ ln2b,
    const float* __restrict__ ln3g, const float* __restrict__ ln3b,
    const float* __restrict__ fW1, const float* __restrict__ fb1,
    const float* __restrict__ fW2, const float* __restrict__ fb2,
    const float* __restrict__ outW, const float* __restrict__ outb,
    float* __restrict__ y){
  __shared__ float sh2[4][128];
  __shared__ float st1[4][128];
  const int tid = threadIdx.x;
  const int w = tid >> 6;
  const int l = tid & 63;
  const int b = blockIdx.x * 4 + w;
  const float* hp = h1pre + (size_t)b * H_;
  const float* cp = capre + (size_t)b * H_;
  float x0 = hp[l], x1 = hp[l+64];
  float m = wsum64(x0 + x1) * (1.0f/128.0f);
  float d0 = x0 - m, d1 = x1 - m;
  float v = wsum64(d0*d0 + d1*d1) * (1.0f/128.0f);
  float rs = rsqrtf(v + 1e-5f);
  float h1a = d0 * rs * ln1g[l]    + ln1b[l];
  float h1b = d1 * rs * ln1g[l+64] + ln1b[l+64];
  x0 = h1a + cp[l]; x1 = h1b + cp[l+64];
  m = wsum64(x0 + x1) * (1.0f/128.0f);
  d0 = x0 - m; d1 = x1 - m;
  v = wsum64(d0*d0 + d1*d1) * (1.0f/128.0f);
  rs = rsqrtf(v + 1e-5f);
  float h2a = d0 * rs * ln2g[l]    + ln2b[l];
  float h2b = d1 * rs * ln2g[l+64] + ln2b[l+64];
  sh2[w][l] = h2a; sh2[w][l+64] = h2b;
  __syncthreads();
  float ta = fb1[l], tb = fb1[l+64];
  #pragma unroll 8
  for (int m4 = 0; m4 < H_; m4 += 4){
    float4 hv = *(const float4*)&sh2[w][m4];
    float4 wa = *(const float4*)&fW1[(size_t)l*H_ + m4];
    float4 wb = *(const float4*)&fW1[(size_t)(l+64)*H_ + m4];
    ta = fmaf(wa.x, hv.x, ta); ta = fmaf(wa.y, hv.y, ta); ta = fmaf(wa.z, hv.z, ta); ta = fmaf(wa.w, hv.w, ta);
    tb = fmaf(wb.x, hv.x, tb); tb = fmaf(wb.y, hv.y, tb); tb = fmaf(wb.z, hv.z, tb); tb = fmaf(wb.w, hv.w, tb);
  }
  ta = fmaxf(ta, 0.0f); tb = fmaxf(tb, 0.0f);
  st1[w][l] = ta; st1[w][l+64] = tb;
  __syncthreads();
  float fa = fb2[l], fbv = fb2[l+64];
  #pragma unroll 8
  for (int m4 = 0; m4 < H_; m4 += 4){
    float4 tv = *(const float4*)&st1[w][m4];
    float4 wa = *(const float4*)&fW2[(size_t)l*H_ + m4];
    float4 wb = *(const float4*)&fW2[(size_t)(l+64)*H_ + m4];
    fa  = fmaf(wa.x, tv.x, fa);  fa  = fmaf(wa.y, tv.y, fa);  fa  = fmaf(wa.z, tv.z, fa);  fa  = fmaf(wa.w, tv.w, fa);
    fbv = fmaf(wb.x, tv.x, fbv); fbv = fmaf(wb.y, tv.y, fbv); fbv = fmaf(wb.z, tv.z, fbv); fbv = fmaf(wb.w, tv.w, fbv);
  }
  x0 = h2a + fa; x1 = h2b + fbv;
  m = wsum64(x0 + x1) * (1.0f/128.0f);
  d0 = x0 - m; d1 = x1 - m;
  v = wsum64(d0*d0 + d1*d1) * (1.0f/128.0f);
  rs = rsqrtf(v + 1e-5f);
  float h3a = d0 * rs * ln3g[l]    + ln3b[l];
  float h3b = d1 * rs * ln3g[l+64] + ln3b[l+64];
  float py = wsum64(outW[l]*h3a + outW[l+64]*h3b);
  if (l == 0) y[b] = py + outb[0];
}

// ---------------- host ----------------
extern "C" void kernel_launch(void* const* d_in, const int* in_sizes, int n_in,
                              void* d_out, int out_size, void* d_ws, size_t ws_size,
                              hipStream_t stream){
  const float* x      = (const float*)d_in[0];
  const float* pxW1   = (const float*)d_in[1];
  const float* pxb1   = (const float*)d_in[2];
  const float* pxW2   = (const float*)d_in[3];
  const float* pxb2   = (const float*)d_in[4];
  const float* embW   = (const float*)d_in[5];
  const float* embb   = (const float*)d_in[6];
  const float* xpW    = (const float*)d_in[7];
  const float* xpb    = (const float*)d_in[8];
  const float* zpW    = (const float*)d_in[9];
  const float* zpb    = (const float*)d_in[10];
  const float* saWqkv = (const float*)d_in[11];
  const float* sabqkv = (const float*)d_in[12];
  const float* saWo   = (const float*)d_in[13];
  const float* sabo   = (const float*)d_in[14];
  const float* caWqkv = (const float*)d_in[15];
  const float* cabqkv = (const float*)d_in[16];
  const float* caWo   = (const float*)d_in[17];
  const float* cabo   = (const float*)d_in[18];
  const float* fW1    = (const float*)d_in[19];
  const float* fb1    = (const float*)d_in[20];
  const float* fW2    = (const float*)d_in[21];
  const float* fb2    = (const float*)d_in[22];
  const float* ln1g   = (const float*)d_in[23];
  const float* ln1b   = (const float*)d_in[24];
  const float* ln2g   = (const float*)d_in[25];
  const float* ln2b   = (const float*)d_in[26];
  const float* ln3g   = (const float*)d_in[27];
  const float* ln3b   = (const float*)d_in[28];
  const float* outW   = (const float*)d_in[29];
  const float* outb   = (const float*)d_in[30];
  (void)in_sizes; (void)n_in; (void)out_size; (void)ws_size;

  float* ws    = (float*)d_ws;
  float* cneg  = ws;                          // 1048576
  float* h1pre = cneg + (size_t)B_*H_;        // 1048576
  float* capre = h1pre + (size_t)B_*H_;       // 1048576
  float* Rm    = capre + (size_t)B_*H_;       // 131072
  float* Sm    = Rm + (size_t)H_*ZD_;         // 16384
  float* Um    = Sm + H_*H_;                  // 16384
  float* Tm    = Um + H_*H_;                  // 8192
  float* vs0   = Tm + H_*XE_;
  float* vu0   = vs0 + H_;
  float* vt0   = vu0 + H_;
  float* vq0   = vt0 + H_;
  float* vr0   = vq0 + H_;
  float* vcb   = vr0 + H_;
  float* Mpart = vcb + H_;                    // 131072
  float* Gpart = Mpart + 131072;              // 262144
  uint32_t* dkeys = (uint32_t*)(Gpart + 262144);  // 32 u32
  float* y0c0  = (float*)(dkeys + 32);        // 2097152 f32
  ushort* WXT   = (ushort*)(y0c0 + (size_t)B_*256);  // 1048576
  ushort* W2bf  = WXT + (size_t)256*XD_;      // 524288
  ushort* Mbf   = W2bf + (size_t)XD_*H_;      // 16384 (=2M)
  ushort* FBT   = Mbf + H_*H_;                // 262144
  ushort* GGr   = FBT + (size_t)256*ZD_;      // 32768
  ushort* hfin  = GGr + (size_t)256*H_;       // 1048576
  ushort* NWR   = hfin + (size_t)B_*H_;       // 20971520 (10 x 8192 x 256)

  float* xre   = (float*)d_out;
  float* ypred = xre + (size_t)B_*XD_;

  k_prepA   <<<512,  64, 0, stream>>>(saWo, saWqkv, caWo, caWqkv, Sm, Um);
  k_prepB   <<<6,    64, 0, stream>>>(saWo, sabqkv, sabo, caWo, cabqkv, cabo, pxW2, pxb2,
                                      vs0, vu0, vcb, dkeys);
  k_prepTR  <<<2180, 64, 0, stream>>>(Sm, Um, xpW, zpW, xpb, zpb, vs0, vu0, Tm, Rm, vt0, vr0);
  k_prepMG_part <<<1536, 256, 0, stream>>>(pxW2, pxW1, Rm, Mpart, Gpart);
  k_prepWXT <<<4096, 256, 0, stream>>>(pxW2, Tm, embW, embb, vt0, WXT, vq0);
  k_conv    <<<3264, 256, 0, stream>>>(pxW2, pxW1, Rm, Mpart, Gpart, W2bf, Mbf, FBT, GGr);
  k_noiseproj <<<1408, 256, 0, stream>>>(FBT, dkeys, y0c0, NWR);
  k_xpass_mfma <<<512, 256, 0, stream>>>(x, WXT, vcb, vq0, cneg, h1pre);
  k_lv2     <<<512, 512, 0, stream>>>(Mbf, GGr, y0c0, NWR, pxb1, vr0, cneg, hfin, capre);
  k_xrecon_mfma <<<4096, 256, 0, stream>>>(hfin, W2bf, pxb2, xre);
  k_tail    <<<2048, 256, 0, stream>>>(h1pre, capre, ln1g, ln1b, ln2g, ln2b, ln3g, ln3b,
                                       fW1, fb1, fW2, fb2, outW, outb, ypred);
}

// Round 14
// 797.895 us; speedup vs baseline: 1.1972x; 1.0958x over previous
//
#include <hip/hip_runtime.h>
#include <hip/hip_bf16.h>
#include <cstdint>
#include <cstddef>
#include <cmath>

#define B_     8192
#define XD_    4096
#define ZD_    1024
#define XE_    64
#define H_     128
#define ZN_    (B_*ZD_)

typedef __attribute__((ext_vector_type(8))) short short8_t;   // 8 x bf16 (4 VGPR)
typedef __attribute__((ext_vector_type(4))) float f32x4_t;    // MFMA accumulator
#define MFMA16(a,b,c) __builtin_amdgcn_mfma_f32_16x16x32_bf16((a),(b),(c),0,0,0)

// ---------------- threefry2x32 (bit-exact vs JAX, partitionable mode — validated R1-R13) ----
__host__ __device__ __forceinline__ uint32_t rotl32_(uint32_t x, int r){
#ifdef __HIP_DEVICE_COMPILE__
  return __builtin_rotateleft32(x, (uint32_t)r);
#else
  return (x<<r)|(x>>(32-r));
#endif
}

__host__ __device__ __forceinline__ void tf2x32(uint32_t k0, uint32_t k1,
                                                uint32_t x0, uint32_t x1,
                                                uint32_t* o0, uint32_t* o1){
  uint32_t k2 = k0 ^ k1 ^ 0x1BD11BDAu;
  x0 += k0; x1 += k1;
  x0 += x1; x1 = rotl32_(x1,13); x1 ^= x0;
  x0 += x1; x1 = rotl32_(x1,15); x1 ^= x0;
  x0 += x1; x1 = rotl32_(x1,26); x1 ^= x0;
  x0 += x1; x1 = rotl32_(x1, 6); x1 ^= x0;
  x0 += k1; x1 += k2 + 1u;
  x0 += x1; x1 = rotl32_(x1,17); x1 ^= x0;
  x0 += x1; x1 = rotl32_(x1,29); x1 ^= x0;
  x0 += x1; x1 = rotl32_(x1,16); x1 ^= x0;
  x0 += x1; x1 = rotl32_(x1,24); x1 ^= x0;
  x0 += k2; x1 += k0 + 2u;
  x0 += x1; x1 = rotl32_(x1,13); x1 ^= x0;
  x0 += x1; x1 = rotl32_(x1,15); x1 ^= x0;
  x0 += x1; x1 = rotl32_(x1,26); x1 ^= x0;
  x0 += x1; x1 = rotl32_(x1, 6); x1 ^= x0;
  x0 += k0; x1 += k1 + 3u;
  x0 += x1; x1 = rotl32_(x1,17); x1 ^= x0;
  x0 += x1; x1 = rotl32_(x1,29); x1 ^= x0;
  x0 += x1; x1 = rotl32_(x1,16); x1 ^= x0;
  x0 += x1; x1 = rotl32_(x1,24); x1 ^= x0;
  x0 += k1; x1 += k2 + 4u;
  x0 += x1; x1 = rotl32_(x1,13); x1 ^= x0;
  x0 += x1; x1 = rotl32_(x1,15); x1 ^= x0;
  x0 += x1; x1 = rotl32_(x1,26); x1 ^= x0;
  x0 += x1; x1 = rotl32_(x1, 6); x1 ^= x0;
  x0 += k2; x1 += k0 + 5u;
  *o0 = x0; *o1 = x1;
}

// XLA ErfInv32; fast v_log (validated R8-R13, absmax unchanged)
__device__ __forceinline__ float erfinv_(float x){
  float w = -__logf(fmaf(-x, x, 1.0f));
  float p;
  if (w < 5.0f){
    w -= 2.5f;
    p = 2.81022636e-08f;
    p = fmaf(p, w, 3.43273939e-07f);
    p = fmaf(p, w, -3.5233877e-06f);
    p = fmaf(p, w, -4.39150654e-06f);
    p = fmaf(p, w, 0.00021858087f);
    p = fmaf(p, w, -0.00125372503f);
    p = fmaf(p, w, -0.00417768164f);
    p = fmaf(p, w, 0.246640727f);
    p = fmaf(p, w, 1.50140941f);
  } else {
    w = sqrtf(w) - 3.0f;
    p = -0.000200214257f;
    p = fmaf(p, w, 0.000100950558f);
    p = fmaf(p, w, 0.00134934322f);
    p = fmaf(p, w, -0.00367342844f);
    p = fmaf(p, w, 0.00573950773f);
    p = fmaf(p, w, -0.0076224613f);
    p = fmaf(p, w, 0.00943887047f);
    p = fmaf(p, w, 1.00167406f);
    p = fmaf(p, w, 2.83297682f);
  }
  return p * x;
}

__device__ __forceinline__ float bits_to_normal(uint32_t bits){
  float f = __uint_as_float((bits >> 9) | 0x3f800000u) - 1.0f;
  float u = fmaxf(-0.99999994f, fmaf(f, 2.0f, -0.99999994f));
  return 1.41421356f * erfinv_(u);
}

__device__ __forceinline__ float rng_normal(uint32_t k0, uint32_t k1, uint32_t idx){
  uint32_t o0, o1; tf2x32(k0, k1, 0u, idx, &o0, &o1);
  return bits_to_normal(o0 ^ o1);
}

__device__ __forceinline__ ushort f2bf(float f){
  return __builtin_bit_cast(ushort, __float2bfloat16(f));
}
__device__ __forceinline__ float bf2f(ushort u){ return __uint_as_float(((uint32_t)u) << 16); }

// 8 bf16 normals (counters base..base+7) into a uint4 (registers)
__device__ __forceinline__ void gen8(uint32_t k0, uint32_t k1, uint32_t base, uint4* g){
  union { ushort u[8]; uint4 q; } pk;
  #pragma unroll
  for (int j = 0; j < 8; ++j) pk.u[j] = f2bf(rng_normal(k0,k1,base+(uint32_t)j));
  *g = pk.q;
}

// ---------------- fused prepA + prepB (independent; one launch) ----------------
__global__ void k_prepAB(const float* __restrict__ saWo, const float* __restrict__ saWqkv,
                         const float* __restrict__ caWo, const float* __restrict__ caWqkv,
                         const float* __restrict__ sabqkv, const float* __restrict__ sabo,
                         const float* __restrict__ cabqkv, const float* __restrict__ cabo,
                         const float* __restrict__ W2, const float* __restrict__ pb2,
                         float* __restrict__ S, float* __restrict__ U,
                         float* __restrict__ s0, float* __restrict__ u0, float* __restrict__ cb,
                         uint32_t* __restrict__ dkeys){
  int blk = blockIdx.x, tid = threadIdx.x;
  if (blk < 512){
    int idx = (blk & 255) * 64 + tid;
    int i = idx >> 7, j = idx & 127;
    if (blk < 256){
      float acc = (i == j) ? 1.0f : 0.0f;
      for (int k = 0; k < H_; ++k) acc += saWo[i*H_ + k] * saWqkv[(2*H_ + k)*H_ + j];
      S[idx] = acc;
    } else {
      float acc = 0.0f;
      for (int k = 0; k < H_; ++k) acc += caWo[i*H_ + k] * caWqkv[(2*H_ + k)*H_ + j];
      U[idx] = acc;
    }
  } else {
    int b2 = blk - 512;
    if (b2 == 0 && tid == 0){
      for (uint32_t i = 0; i < 11; ++i){
        uint32_t a, b; tf2x32(0u, 42u, 0u, i, &a, &b);
        dkeys[2*i] = a; dkeys[2*i+1] = b;
      }
    }
    if (b2 < 2){
      int i = b2*64 + tid;
      float acc = sabo[i];
      for (int k = 0; k < H_; ++k) acc += saWo[i*H_ + k] * sabqkv[2*H_ + k];
      s0[i] = acc;
    } else if (b2 < 4){
      int i = (b2-2)*64 + tid;
      float acc = cabo[i];
      for (int k = 0; k < H_; ++k) acc += caWo[i*H_ + k] * cabqkv[2*H_ + k];
      u0[i] = acc;
    } else {
      int j = (b2-4)*64 + tid;
      float acc = 0.0f;
      for (int c = 0; c < XD_; ++c) acc += pb2[c] * W2[(size_t)c*H_ + j];
      cb[j] = acc;
    }
  }
}

__global__ void k_prepTR(const float* __restrict__ S, const float* __restrict__ U,
                         const float* __restrict__ xpW, const float* __restrict__ zpW,
                         const float* __restrict__ xpb, const float* __restrict__ zpb,
                         const float* __restrict__ s0, const float* __restrict__ u0,
                         float* __restrict__ T, float* __restrict__ R,
                         float* __restrict__ t0, float* __restrict__ r0v){
  int blk = blockIdx.x, tid = threadIdx.x;
  if (blk < 128){
    int idx = blk*64 + tid;
    int i = idx >> 6, e = idx & 63;
    float acc = 0.0f;
    for (int m = 0; m < H_; ++m) acc += S[i*H_ + m] * xpW[m*XE_ + e];
    T[idx] = acc;
  } else if (blk < 2176){
    int idx = (blk-128)*64 + tid;
    int i = idx >> 10, k = idx & 1023;
    float acc = 0.0f;
    for (int m = 0; m < H_; ++m) acc += U[i*H_ + m] * zpW[(size_t)m*ZD_ + k];
    R[idx] = acc;
  } else if (blk < 2178){
    int i = (blk-2176)*64 + tid;
    float acc = s0[i];
    for (int m = 0; m < H_; ++m) acc += S[i*H_ + m] * xpb[m];
    t0[i] = acc;
  } else {
    int i = (blk-2178)*64 + tid;
    float acc = u0[i];
    for (int m = 0; m < H_; ++m) acc += U[i*H_ + m] * zpb[m];
    r0v[i] = acc;
  }
}

// ---------------- fused prepWXT + prepMG_part (both depend only on prepTR) ----------------
__global__ void k_prepWM(const float* __restrict__ W2, const float* __restrict__ T,
                         const float* __restrict__ embW, const float* __restrict__ embb,
                         const float* __restrict__ t0, const float* __restrict__ W1,
                         const float* __restrict__ R,
                         ushort* __restrict__ WXT, float* __restrict__ q0,
                         float* __restrict__ Mpart, float* __restrict__ Gpart){
  if (blockIdx.x < 4096){
    int idx = blockIdx.x*256 + threadIdx.x;   // 1048576
    int j = idx >> 12, c = idx & 4095;
    float v;
    if (j < H_) v = W2[(size_t)c*H_ + j];
    else {
      int i = j - H_;
      float acc = 0.0f;
      for (int e = 0; e < XE_; ++e) acc += T[i*XE_ + e] * embW[(size_t)e*XD_ + c];
      v = acc;
    }
    WXT[idx] = f2bf(v);
    if (idx < H_){
      float acc = t0[idx];
      for (int e = 0; e < XE_; ++e) acc += T[idx*XE_ + e] * embb[e];
      q0[idx] = acc;
    }
  } else {
    int gid = (blockIdx.x - 4096)*256 + threadIdx.x;   // 393216
    if (gid < 131072){
      int slice = gid >> 14, i = gid & 16383;
      int j1 = i >> 7, j2 = i & 127;
      int c0 = slice*512;
      float acc = 0.0f;
      for (int c = c0; c < c0+512; ++c)
        acc += W2[(size_t)c*H_ + j1] * W2[(size_t)c*H_ + j2];
      Mpart[(size_t)slice*16384 + i] = acc;
    } else {
      int g = gid - 131072;
      int slice = g >> 15, i2 = g & 32767;
      int i = i2 >> 7, k = i2 & 127;
      int m0 = slice*128;
      float acc = 0.0f;
      if (i < 128){
        for (int m = m0; m < m0+128; ++m)
          acc += W1[(size_t)i*ZD_ + m] * W1[(size_t)k*ZD_ + m];
      } else {
        for (int m = m0; m < m0+128; ++m)
          acc += W1[(size_t)k*ZD_ + m] * R[(size_t)(i-128)*ZD_ + m];
      }
      Gpart[(size_t)slice*32768 + i2] = acc;
    }
  }
}

// W2bf[524288]; Mbf=f2bf(2*sum Mpart)[16384]; FBTswz (fragment-ordered, see below)[262144];
// GGr=f2bf(-0.005*sum Gpart)[32768].
// FBTswz layout: elem(((cf*32)+(it*2+h))*64+lane)*8+j = FBT_lin[(cf*16+(lane&15))*1024
//   + it*64 + h*32 + (lane>>4)*8 + j] — so each noiseproj B-load is 64 lanes x
//   consecutive 16B = one fully coalesced 1KB request (was 16 x 64B at 2KB stride).
__global__ void k_conv(const float* __restrict__ W2, const float* __restrict__ W1,
                       const float* __restrict__ R,
                       const float* __restrict__ Mpart, const float* __restrict__ Gpart,
                       ushort* __restrict__ W2bf, ushort* __restrict__ Mbf,
                       ushort* __restrict__ FBT, ushort* __restrict__ GGr){
  int idx = blockIdx.x*256 + threadIdx.x;   // 835584
  if (idx < 524288) W2bf[idx] = f2bf(W2[idx]);
  else if (idx < 540672){
    int i = idx - 524288;
    float s = 0.0f;
    #pragma unroll
    for (int p = 0; p < 8; ++p) s += Mpart[(size_t)p*16384 + i];
    Mbf[i] = f2bf(2.0f*s);
  } else if (idx < 802816){
    int i = idx - 540672;                 // 0..262143, swizzled dest index
    int j    = i & 7;
    int lane = (i >> 3) & 63;
    int hh   = (i >> 9) & 1;
    int itt  = (i >> 10) & 15;
    int cf   = i >> 14;
    int srow = cf*16 + (lane & 15);
    int scol = itt*64 + hh*32 + ((lane >> 4) << 3) + j;
    float v = (srow < H_) ? W1[(size_t)srow*ZD_ + scol] : R[(size_t)(srow-H_)*ZD_ + scol];
    FBT[i] = f2bf(v);
  } else {
    int i = idx - 802816;
    float s = 0.0f;
    #pragma unroll
    for (int p = 0; p < 8; ++p) s += Gpart[(size_t)p*32768 + i];
    GGr[i] = f2bf(-0.005f*s);
  }
}

// ---------------- noise projection: pass p rows [8192][1024] RNG @ FBT^T -> [8192][256]
// R13 post-mortem: load-hoist helped (440->397) but VALU stuck at 68.5% — B-loads
// were 16x 64B-fragments at 2KB stride (L1/TA transaction pressure, invisible in
// HBM counters since all L2-hit). Fix: FBTswz fragment-ordered layout -> each
// B-load is one coalesced 1KB request; address math collapses to base+stride.
__global__ __launch_bounds__(256) void k_noiseproj(
    const ushort* __restrict__ FBT, const uint32_t* __restrict__ dkeys,
    float* __restrict__ y0c0, ushort* __restrict__ NWR){
  const int t = threadIdx.x, lane = t & 63, w = t >> 6;
  const int l15 = lane & 15, rq = (lane >> 4)*4, kq8 = (lane >> 4)*8;
  (void)kq8;
  const int gwid = blockIdx.x*4 + w;         // 0..5631
  const int p = gwid >> 9, mb = gwid & 511;  // 11 passes x 512 row-tiles of 16
  const int row0 = mb*16;
  const uint32_t k0 = dkeys[2*p], k1 = dkeys[2*p+1];
  const uint32_t rbase = (uint32_t)(row0 + l15)*1024u + (uint32_t)((lane >> 4)*8);
  f32x4_t acc[16] = {};
  #pragma unroll 1
  for (int it = 0; it < 16; ++it){
    uint4 br[16];
    // ---- h=0: issue all 16 coalesced B loads, pin, RNG covers latency
    {
      const ushort* fb = FBT + (size_t)(it*2)*512 + lane*8;
      #pragma unroll
      for (int cf = 0; cf < 16; ++cf) br[cf] = *(const uint4*)(fb + (size_t)cf*16384);
    }
    __builtin_amdgcn_sched_barrier(0);
    uint4 g0; gen8(k0, k1, rbase + (uint32_t)(it*64), &g0);
    short8_t a0 = __builtin_bit_cast(short8_t, g0);
    #pragma unroll
    for (int cf = 0; cf < 16; ++cf)
      acc[cf] = MFMA16(a0, __builtin_bit_cast(short8_t, br[cf]), acc[cf]);
    // ---- h=1
    {
      const ushort* fb = FBT + (size_t)(it*2+1)*512 + lane*8;
      #pragma unroll
      for (int cf = 0; cf < 16; ++cf) br[cf] = *(const uint4*)(fb + (size_t)cf*16384);
    }
    __builtin_amdgcn_sched_barrier(0);
    uint4 g1; gen8(k0, k1, rbase + (uint32_t)(it*64 + 32), &g1);
    short8_t a1 = __builtin_bit_cast(short8_t, g1);
    #pragma unroll
    for (int cf = 0; cf < 16; ++cf)
      acc[cf] = MFMA16(a1, __builtin_bit_cast(short8_t, br[cf]), acc[cf]);
  }
  #pragma unroll
  for (int cf = 0; cf < 16; ++cf){
    int col = cf*16 + l15;
    #pragma unroll
    for (int r = 0; r < 4; ++r){
      int row = row0 + rq + r;
      float v = acc[cf][r];
      if (p == 0) y0c0[(size_t)row*256 + col] = v;
      else NWR[(size_t)(p-1)*2097152 + (size_t)row*256 + col] = f2bf(0.1f*v);
    }
  }
}

// ---------------- x-pass (MFMA, dbuf, 1 barrier/iter): [cneg | h1pre] = x @ WXT^T ----
// BM=32, BN=128, grid 512, 256 thr. Carried-register prefetch (R8-proven).
__global__ __launch_bounds__(256) void k_xpass_mfma(
    const float* __restrict__ x, const ushort* __restrict__ WXT,
    const float* __restrict__ cb, const float* __restrict__ q0,
    float* __restrict__ cneg, float* __restrict__ h1pre){
  __shared__ __align__(16) ushort xt[2][32*72];
  __shared__ __align__(16) ushort bt[2][128*72];
  const int t = threadIdx.x, lane = t & 63, w = t >> 6;
  const int bm = blockIdx.x >> 1, bn = blockIdx.x & 1;
  const int row0 = bm*32, ncol0 = bn*128;
  const int l15 = lane & 15, kq8 = (lane >> 4)*8, rq = (lane >> 4)*4;
  const int rt = w & 1, cb4 = (w >> 1)*4;
  const int xr = t >> 3, xk = (t & 7)*8;
  const int wn = t >> 1, wk = (t & 1)*32;
  f32x4_t acc[4] = {};
  {
    float4 v0 = *(const float4*)&x[(size_t)(row0+xr)*XD_ + xk];
    float4 v1 = *(const float4*)&x[(size_t)(row0+xr)*XD_ + xk + 4];
    union { ushort u[8]; uint4 q; } p;
    p.u[0]=f2bf(v0.x); p.u[1]=f2bf(v0.y); p.u[2]=f2bf(v0.z); p.u[3]=f2bf(v0.w);
    p.u[4]=f2bf(v1.x); p.u[5]=f2bf(v1.y); p.u[6]=f2bf(v1.z); p.u[7]=f2bf(v1.w);
    *(uint4*)&xt[0][xr*72 + xk] = p.q;
    const ushort* s = &WXT[(size_t)(ncol0+wn)*XD_ + wk];
    uint4 b0v=*(const uint4*)s, b1v=*(const uint4*)(s+8), b2v=*(const uint4*)(s+16), b3v=*(const uint4*)(s+24);
    ushort* d = &bt[0][wn*72 + wk];
    *(uint4*)d=b0v; *(uint4*)(d+8)=b1v; *(uint4*)(d+16)=b2v; *(uint4*)(d+24)=b3v;
  }
  float4 xv0, xv1; uint4 wb0, wb1, wb2, wb3;
  {
    xv0 = *(const float4*)&x[(size_t)(row0+xr)*XD_ + 64 + xk];
    xv1 = *(const float4*)&x[(size_t)(row0+xr)*XD_ + 64 + xk + 4];
    const ushort* s = &WXT[(size_t)(ncol0+wn)*XD_ + 64 + wk];
    wb0=*(const uint4*)s; wb1=*(const uint4*)(s+8); wb2=*(const uint4*)(s+16); wb3=*(const uint4*)(s+24);
  }
  #pragma unroll 1
  for (int it = 0; it < 64; ++it){
    __syncthreads();
    if (it < 63){
      union { ushort u[8]; uint4 q; } p;
      p.u[0]=f2bf(xv0.x); p.u[1]=f2bf(xv0.y); p.u[2]=f2bf(xv0.z); p.u[3]=f2bf(xv0.w);
      p.u[4]=f2bf(xv1.x); p.u[5]=f2bf(xv1.y); p.u[6]=f2bf(xv1.z); p.u[7]=f2bf(xv1.w);
      *(uint4*)&xt[(it+1)&1][xr*72 + xk] = p.q;
      ushort* d = &bt[(it+1)&1][wn*72 + wk];
      *(uint4*)d=wb0; *(uint4*)(d+8)=wb1; *(uint4*)(d+16)=wb2; *(uint4*)(d+24)=wb3;
    }
    if (it < 62){
      const int kt = (it+2)*64;
      xv0 = *(const float4*)&x[(size_t)(row0+xr)*XD_ + kt + xk];
      xv1 = *(const float4*)&x[(size_t)(row0+xr)*XD_ + kt + xk + 4];
      const ushort* s = &WXT[(size_t)(ncol0+wn)*XD_ + kt + wk];
      wb0=*(const uint4*)s; wb1=*(const uint4*)(s+8); wb2=*(const uint4*)(s+16); wb3=*(const uint4*)(s+24);
    }
    const ushort* xb = &xt[it&1][(rt*16+l15)*72];
    const ushort* bb = &bt[it&1][0];
    #pragma unroll
    for (int h = 0; h < 2; ++h){
      short8_t a = *(const short8_t*)(xb + h*32 + kq8);
      #pragma unroll
      for (int c = 0; c < 4; ++c){
        short8_t b = *(const short8_t*)(bb + ((cb4+c)*16+l15)*72 + h*32 + kq8);
        acc[c] = MFMA16(a, b, acc[c]);
      }
    }
  }
  #pragma unroll
  for (int c = 0; c < 4; ++c){
    int jl = (cb4+c)*16 + l15;
    #pragma unroll
    for (int r = 0; r < 4; ++r){
      int row = row0 + rt*16 + rq + r;
      float v = acc[c][r];
      if (bn == 0) cneg[(size_t)row*H_ + jl] = 2.0f*(cb[jl] - v);
      else         h1pre[(size_t)row*H_ + jl] = v + q0[jl];
    }
  }
}

// ---------------- 128-dim Langevin: yc state in f32 MFMA accumulators ----------------
__global__ __launch_bounds__(512) void k_lv2(
    const ushort* __restrict__ M2bf, const ushort* __restrict__ GGr,
    const float* __restrict__ y0c0, const ushort* __restrict__ NWR,
    const float* __restrict__ b1, const float* __restrict__ r0v,
    const float* __restrict__ cneg,
    ushort* __restrict__ hfin_bf, float* __restrict__ capre){
  __shared__ __align__(16) ushort abuf[16*136];
  __shared__ __align__(16) ushort glbuf[16*136];
  const int t = threadIdx.x, lane = t & 63, w = t >> 6;
  const int l15 = lane & 15, kq8 = (lane >> 4)*8, rq = (lane >> 4)*4;
  const int b0 = blockIdx.x * 16;
  const int myc = w*16 + l15;
  const int col2 = w*32 + l15;

  f32x4_t acc[2];
  #pragma unroll
  for (int nf = 0; nf < 2; ++nf)
    #pragma unroll
    for (int r = 0; r < 4; ++r)
      acc[nf][r] = y0c0[(size_t)(b0+rq+r)*256 + col2 + nf*16];
  float cn[4];
  #pragma unroll
  for (int r = 0; r < 4; ++r) cn[r] = cneg[(size_t)(b0+rq+r)*H_ + myc];
  float bb2[2];
  bb2[0] = (w < 4) ? b1[col2] : 0.0f;
  bb2[1] = (w < 4) ? b1[col2+16] : 0.0f;
  ushort nx[8];
  #pragma unroll
  for (int nf = 0; nf < 2; ++nf)
    #pragma unroll
    for (int r = 0; r < 4; ++r)
      nx[nf*4+r] = NWR[(size_t)(b0+rq+r)*256 + col2 + nf*16];

  #pragma unroll 1
  for (int s = 0; s < 10; ++s){
    if (w < 4){
      #pragma unroll
      for (int nf = 0; nf < 2; ++nf)
        #pragma unroll
        for (int r = 0; r < 4; ++r)
          abuf[(rq+r)*136 + col2 + nf*16] = f2bf(fmaxf(acc[nf][r] + bb2[nf], 0.0f));
    }
    __syncthreads();
    f32x4_t g2 = {};
    #pragma unroll
    for (int h = 0; h < 4; ++h){
      short8_t a = *(const short8_t*)&abuf[l15*136 + h*32 + kq8];
      short8_t b = *(const short8_t*)&M2bf[(size_t)myc*H_ + h*32 + kq8];
      g2 = MFMA16(a, b, g2);
    }
    #pragma unroll
    for (int r = 0; r < 4; ++r){
      float g = (abuf[(rq+r)*136 + myc] != 0) ? (g2[r] + cn[r]) : 0.0f;
      glbuf[(rq+r)*136 + myc] = f2bf(g);
    }
    __syncthreads();
    #pragma unroll
    for (int nf = 0; nf < 2; ++nf)
      #pragma unroll
      for (int h = 0; h < 4; ++h){
        short8_t a = *(const short8_t*)&glbuf[l15*136 + h*32 + kq8];
        short8_t b = *(const short8_t*)&GGr[(size_t)(col2 + nf*16)*H_ + h*32 + kq8];
        acc[nf] = MFMA16(a, b, acc[nf]);
      }
    #pragma unroll
    for (int nf = 0; nf < 2; ++nf)
      #pragma unroll
      for (int r = 0; r < 4; ++r)
        acc[nf][r] += bf2f(nx[nf*4+r]);
    if (s < 9){
      #pragma unroll
      for (int nf = 0; nf < 2; ++nf)
        #pragma unroll
        for (int r = 0; r < 4; ++r)
          nx[nf*4+r] = NWR[(size_t)(s+1)*2097152 + (size_t)(b0+rq+r)*256 + col2 + nf*16];
    }
    __syncthreads();
  }
  if (w < 4){
    #pragma unroll
    for (int nf = 0; nf < 2; ++nf)
      #pragma unroll
      for (int r = 0; r < 4; ++r)
        hfin_bf[(size_t)(b0+rq+r)*H_ + col2 + nf*16] = f2bf(fmaxf(acc[nf][r] + bb2[nf], 0.0f));
  } else {
    #pragma unroll
    for (int nf = 0; nf < 2; ++nf)
      #pragma unroll
      for (int r = 0; r < 4; ++r)
        capre[(size_t)(b0+rq+r)*H_ + (col2 + nf*16 - 128)] = acc[nf][r] + r0v[col2 + nf*16 - 128];
  }
}

// ---------------- x_recon (MFMA): out = hfin @ W2^T + b2 ----------------
__global__ __launch_bounds__(256) void k_xrecon_mfma(
    const ushort* __restrict__ hfin_bf, const ushort* __restrict__ W2bf,
    const float* __restrict__ b2, float* __restrict__ out){
  __shared__ __align__(16) ushort at[64*136];
  __shared__ __align__(16) ushort bt[128*136];
  const int tid = threadIdx.x, lane = tid & 63, w = tid >> 6;
  const int bm = blockIdx.x >> 5, bn = blockIdx.x & 31;
  const int row0 = bm*64, c0 = bn*128;
  const int l15 = lane & 15, kq8 = (lane >> 4)*8, rq = (lane >> 4)*4;
  { int r = tid >> 2, kq = (tid & 3)*32;
    const ushort* src = &hfin_bf[(size_t)(row0 + r)*H_ + kq];
    #pragma unroll
    for (int i = 0; i < 4; ++i) *(uint4*)&at[r*136 + kq + 8*i] = *(const uint4*)(src + 8*i);
  }
  { int n = tid >> 1, kh = (tid & 1)*64;
    const ushort* src = &W2bf[(size_t)(c0 + n)*H_ + kh];
    #pragma unroll
    for (int i = 0; i < 8; ++i) *(uint4*)&bt[n*136 + kh + 8*i] = *(const uint4*)(src + 8*i);
  }
  __syncthreads();
  f32x4_t acc[8] = {};
  #pragma unroll
  for (int k = 0; k < 4; ++k){
    short8_t a = *(const short8_t*)&at[(w*16 + l15)*136 + k*32 + kq8];
    #pragma unroll
    for (int nf = 0; nf < 8; ++nf){
      short8_t b = *(const short8_t*)&bt[(nf*16 + l15)*136 + k*32 + kq8];
      acc[nf] = MFMA16(a, b, acc[nf]);
    }
  }
  #pragma unroll
  for (int nf = 0; nf < 8; ++nf){
    int c = c0 + nf*16 + l15;
    float bbv = b2[c];
    #pragma unroll
    for (int r = 0; r < 4; ++r){
      int row = row0 + w*16 + rq + r;
      out[(size_t)row*XD_ + c] = acc[nf][r] + bbv;
    }
  }
}

// ---------------- per-row transformer tail -> y_pred ----------------
__device__ __forceinline__ float wsum64(float v){
  #pragma unroll
  for (int off = 32; off > 0; off >>= 1) v += __shfl_xor(v, off, 64);
  return v;
}

__global__ __launch_bounds__(256) void k_tail(
    const float* __restrict__ h1pre, const float* __restrict__ capre,
    const float* __restrict__ ln1g, const float* __restrict__ ln1b,
    const float* __restrict__ ln2g, const float* __restrict__ ln2b,
    const float* __restrict__ ln3g, const float* __restrict__ ln3b,
    const float* __restrict__ fW1, const float* __restrict__ fb1,
    const float* __restrict__ fW2, const float* __restrict__ fb2,
    const float* __restrict__ outW, const float* __restrict__ outb,
    float* __restrict__ y){
  __shared__ float sh2[4][128];
  __shared__ float st1[4][128];
  const int tid = threadIdx.x;
  const int w = tid >> 6;
  const int l = tid & 63;
  const int b = blockIdx.x * 4 + w;
  const float* hp = h1pre + (size_t)b * H_;
  const float* cp = capre + (size_t)b * H_;
  float x0 = hp[l], x1 = hp[l+64];
  float m = wsum64(x0 + x1) * (1.0f/128.0f);
  float d0 = x0 - m, d1 = x1 - m;
  float v = wsum64(d0*d0 + d1*d1) * (1.0f/128.0f);
  float rs = rsqrtf(v + 1e-5f);
  float h1a = d0 * rs * ln1g[l]    + ln1b[l];
  float h1b = d1 * rs * ln1g[l+64] + ln1b[l+64];
  x0 = h1a + cp[l]; x1 = h1b + cp[l+64];
  m = wsum64(x0 + x1) * (1.0f/128.0f);
  d0 = x0 - m; d1 = x1 - m;
  v = wsum64(d0*d0 + d1*d1) * (1.0f/128.0f);
  rs = rsqrtf(v + 1e-5f);
  float h2a = d0 * rs * ln2g[l]    + ln2b[l];
  float h2b = d1 * rs * ln2g[l+64] + ln2b[l+64];
  sh2[w][l] = h2a; sh2[w][l+64] = h2b;
  __syncthreads();
  float ta = fb1[l], tb = fb1[l+64];
  #pragma unroll 8
  for (int m4 = 0; m4 < H_; m4 += 4){
    float4 hv = *(const float4*)&sh2[w][m4];
    float4 wa = *(const float4*)&fW1[(size_t)l*H_ + m4];
    float4 wb = *(const float4*)&fW1[(size_t)(l+64)*H_ + m4];
    ta = fmaf(wa.x, hv.x, ta); ta = fmaf(wa.y, hv.y, ta); ta = fmaf(wa.z, hv.z, ta); ta = fmaf(wa.w, hv.w, ta);
    tb = fmaf(wb.x, hv.x, tb); tb = fmaf(wb.y, hv.y, tb); tb = fmaf(wb.z, hv.z, tb); tb = fmaf(wb.w, hv.w, tb);
  }
  ta = fmaxf(ta, 0.0f); tb = fmaxf(tb, 0.0f);
  st1[w][l] = ta; st1[w][l+64] = tb;
  __syncthreads();
  float fa = fb2[l], fbv = fb2[l+64];
  #pragma unroll 8
  for (int m4 = 0; m4 < H_; m4 += 4){
    float4 tv = *(const float4*)&st1[w][m4];
    float4 wa = *(const float4*)&fW2[(size_t)l*H_ + m4];
    float4 wb = *(const float4*)&fW2[(size_t)(l+64)*H_ + m4];
    fa  = fmaf(wa.x, tv.x, fa);  fa  = fmaf(wa.y, tv.y, fa);  fa  = fmaf(wa.z, tv.z, fa);  fa  = fmaf(wa.w, tv.w, fa);
    fbv = fmaf(wb.x, tv.x, fbv); fbv = fmaf(wb.y, tv.y, fbv); fbv = fmaf(wb.z, tv.z, fbv); fbv = fmaf(wb.w, tv.w, fbv);
  }
  x0 = h2a + fa; x1 = h2b + fbv;
  m = wsum64(x0 + x1) * (1.0f/128.0f);
  d0 = x0 - m; d1 = x1 - m;
  v = wsum64(d0*d0 + d1*d1) * (1.0f/128.0f);
  rs = rsqrtf(v + 1e-5f);
  float h3a = d0 * rs * ln3g[l]    + ln3b[l];
  float h3b = d1 * rs * ln3g[l+64] + ln3b[l+64];
  float py = wsum64(outW[l]*h3a + outW[l+64]*h3b);
  if (l == 0) y[b] = py + outb[0];
}

// ---------------- host ----------------
extern "C" void kernel_launch(void* const* d_in, const int* in_sizes, int n_in,
                              void* d_out, int out_size, void* d_ws, size_t ws_size,
                              hipStream_t stream){
  const float* x      = (const float*)d_in[0];
  const float* pxW1   = (const float*)d_in[1];
  const float* pxb1   = (const float*)d_in[2];
  const float* pxW2   = (const float*)d_in[3];
  const float* pxb2   = (const float*)d_in[4];
  const float* embW   = (const float*)d_in[5];
  const float* embb   = (const float*)d_in[6];
  const float* xpW    = (const float*)d_in[7];
  const float* xpb    = (const float*)d_in[8];
  const float* zpW    = (const float*)d_in[9];
  const float* zpb    = (const float*)d_in[10];
  const float* saWqkv = (const float*)d_in[11];
  const float* sabqkv = (const float*)d_in[12];
  const float* saWo   = (const float*)d_in[13];
  const float* sabo   = (const float*)d_in[14];
  const float* caWqkv = (const float*)d_in[15];
  const float* cabqkv = (const float*)d_in[16];
  const float* caWo   = (const float*)d_in[17];
  const float* cabo   = (const float*)d_in[18];
  const float* fW1    = (const float*)d_in[19];
  const float* fb1    = (const float*)d_in[20];
  const float* fW2    = (const float*)d_in[21];
  const float* fb2    = (const float*)d_in[22];
  const float* ln1g   = (const float*)d_in[23];
  const float* ln1b   = (const float*)d_in[24];
  const float* ln2g   = (const float*)d_in[25];
  const float* ln2b   = (const float*)d_in[26];
  const float* ln3g   = (const float*)d_in[27];
  const float* ln3b   = (const float*)d_in[28];
  const float* outW   = (const float*)d_in[29];
  const float* outb   = (const float*)d_in[30];
  (void)in_sizes; (void)n_in; (void)out_size; (void)ws_size;

  float* ws    = (float*)d_ws;
  float* cneg  = ws;                          // 1048576
  float* h1pre = cneg + (size_t)B_*H_;        // 1048576
  float* capre = h1pre + (size_t)B_*H_;       // 1048576
  float* Rm    = capre + (size_t)B_*H_;       // 131072
  float* Sm    = Rm + (size_t)H_*ZD_;         // 16384
  float* Um    = Sm + H_*H_;                  // 16384
  float* Tm    = Um + H_*H_;                  // 8192
  float* vs0   = Tm + H_*XE_;
  float* vu0   = vs0 + H_;
  float* vt0   = vu0 + H_;
  float* vq0   = vt0 + H_;
  float* vr0   = vq0 + H_;
  float* vcb   = vr0 + H_;
  float* Mpart = vcb + H_;                    // 131072
  float* Gpart = Mpart + 131072;              // 262144
  uint32_t* dkeys = (uint32_t*)(Gpart + 262144);  // 32 u32
  float* y0c0  = (float*)(dkeys + 32);        // 2097152 f32
  ushort* WXT   = (ushort*)(y0c0 + (size_t)B_*256);  // 1048576
  ushort* W2bf  = WXT + (size_t)256*XD_;      // 524288
  ushort* Mbf   = W2bf + (size_t)XD_*H_;      // 16384 (=2M)
  ushort* FBT   = Mbf + H_*H_;                // 262144 (fragment-ordered swz)
  ushort* GGr   = FBT + (size_t)256*ZD_;      // 32768
  ushort* hfin  = GGr + (size_t)256*H_;       // 1048576
  ushort* NWR   = hfin + (size_t)B_*H_;       // 20971520 (10 x 8192 x 256)

  float* xre   = (float*)d_out;
  float* ypred = xre + (size_t)B_*XD_;

  k_prepAB  <<<518,  64, 0, stream>>>(saWo, saWqkv, caWo, caWqkv, sabqkv, sabo,
                                      cabqkv, cabo, pxW2, pxb2, Sm, Um, vs0, vu0, vcb, dkeys);
  k_prepTR  <<<2180, 64, 0, stream>>>(Sm, Um, xpW, zpW, xpb, zpb, vs0, vu0, Tm, Rm, vt0, vr0);
  k_prepWM  <<<5632, 256, 0, stream>>>(pxW2, Tm, embW, embb, vt0, pxW1, Rm,
                                       WXT, vq0, Mpart, Gpart);
  k_conv    <<<3264, 256, 0, stream>>>(pxW2, pxW1, Rm, Mpart, Gpart, W2bf, Mbf, FBT, GGr);
  k_noiseproj <<<1408, 256, 0, stream>>>(FBT, dkeys, y0c0, NWR);
  k_xpass_mfma <<<512, 256, 0, stream>>>(x, WXT, vcb, vq0, cneg, h1pre);
  k_lv2     <<<512, 512, 0, stream>>>(Mbf, GGr, y0c0, NWR, pxb1, vr0, cneg, hfin, capre);
  k_xrecon_mfma <<<4096, 256, 0, stream>>>(hfin, W2bf, pxb2, xre);
  k_tail    <<<2048, 256, 0, stream>>>(h1pre, capre, ln1g, ln1b, ln2g, ln2b, ln3g, ln3b,
                                       fW1, fb1, fW2, fb2, outW, outb, ypred);
}

// Round 15
// 779.943 us; speedup vs baseline: 1.2247x; 1.0230x over previous
//
#include <hip/hip_runtime.h>
#include <hip/hip_bf16.h>
#include <cstdint>
#include <cstddef>
#include <cmath>

#define B_     8192
#define XD_    4096
#define ZD_    1024
#define XE_    64
#define H_     128
#define ZN_    (B_*ZD_)

typedef __attribute__((ext_vector_type(8))) short short8_t;   // 8 x bf16 (4 VGPR)
typedef __attribute__((ext_vector_type(4))) float f32x4_t;    // MFMA accumulator
#define MFMA16(a,b,c) __builtin_amdgcn_mfma_f32_16x16x32_bf16((a),(b),(c),0,0,0)

// ---------------- threefry2x32 (bit-exact vs JAX, partitionable mode — validated R1-R14) ----
__host__ __device__ __forceinline__ uint32_t rotl32_(uint32_t x, int r){
#ifdef __HIP_DEVICE_COMPILE__
  return __builtin_rotateleft32(x, (uint32_t)r);
#else
  return (x<<r)|(x>>(32-r));
#endif
}

__host__ __device__ __forceinline__ void tf2x32(uint32_t k0, uint32_t k1,
                                                uint32_t x0, uint32_t x1,
                                                uint32_t* o0, uint32_t* o1){
  uint32_t k2 = k0 ^ k1 ^ 0x1BD11BDAu;
  x0 += k0; x1 += k1;
  x0 += x1; x1 = rotl32_(x1,13); x1 ^= x0;
  x0 += x1; x1 = rotl32_(x1,15); x1 ^= x0;
  x0 += x1; x1 = rotl32_(x1,26); x1 ^= x0;
  x0 += x1; x1 = rotl32_(x1, 6); x1 ^= x0;
  x0 += k1; x1 += k2 + 1u;
  x0 += x1; x1 = rotl32_(x1,17); x1 ^= x0;
  x0 += x1; x1 = rotl32_(x1,29); x1 ^= x0;
  x0 += x1; x1 = rotl32_(x1,16); x1 ^= x0;
  x0 += x1; x1 = rotl32_(x1,24); x1 ^= x0;
  x0 += k2; x1 += k0 + 2u;
  x0 += x1; x1 = rotl32_(x1,13); x1 ^= x0;
  x0 += x1; x1 = rotl32_(x1,15); x1 ^= x0;
  x0 += x1; x1 = rotl32_(x1,26); x1 ^= x0;
  x0 += x1; x1 = rotl32_(x1, 6); x1 ^= x0;
  x0 += k0; x1 += k1 + 3u;
  x0 += x1; x1 = rotl32_(x1,17); x1 ^= x0;
  x0 += x1; x1 = rotl32_(x1,29); x1 ^= x0;
  x0 += x1; x1 = rotl32_(x1,16); x1 ^= x0;
  x0 += x1; x1 = rotl32_(x1,24); x1 ^= x0;
  x0 += k1; x1 += k2 + 4u;
  x0 += x1; x1 = rotl32_(x1,13); x1 ^= x0;
  x0 += x1; x1 = rotl32_(x1,15); x1 ^= x0;
  x0 += x1; x1 = rotl32_(x1,26); x1 ^= x0;
  x0 += x1; x1 = rotl32_(x1, 6); x1 ^= x0;
  x0 += k2; x1 += k0 + 5u;
  *o0 = x0; *o1 = x1;
}

// XLA ErfInv32; fast v_log (validated R8-R14, absmax unchanged)
__device__ __forceinline__ float erfinv_(float x){
  float w = -__logf(fmaf(-x, x, 1.0f));
  float p;
  if (w < 5.0f){
    w -= 2.5f;
    p = 2.81022636e-08f;
    p = fmaf(p, w, 3.43273939e-07f);
    p = fmaf(p, w, -3.5233877e-06f);
    p = fmaf(p, w, -4.39150654e-06f);
    p = fmaf(p, w, 0.00021858087f);
    p = fmaf(p, w, -0.00125372503f);
    p = fmaf(p, w, -0.00417768164f);
    p = fmaf(p, w, 0.246640727f);
    p = fmaf(p, w, 1.50140941f);
  } else {
    w = sqrtf(w) - 3.0f;
    p = -0.000200214257f;
    p = fmaf(p, w, 0.000100950558f);
    p = fmaf(p, w, 0.00134934322f);
    p = fmaf(p, w, -0.00367342844f);
    p = fmaf(p, w, 0.00573950773f);
    p = fmaf(p, w, -0.0076224613f);
    p = fmaf(p, w, 0.00943887047f);
    p = fmaf(p, w, 1.00167406f);
    p = fmaf(p, w, 2.83297682f);
  }
  return p * x;
}

__device__ __forceinline__ float bits_to_normal(uint32_t bits){
  float f = __uint_as_float((bits >> 9) | 0x3f800000u) - 1.0f;
  float u = fmaxf(-0.99999994f, fmaf(f, 2.0f, -0.99999994f));
  return 1.41421356f * erfinv_(u);
}

__device__ __forceinline__ float rng_normal(uint32_t k0, uint32_t k1, uint32_t idx){
  uint32_t o0, o1; tf2x32(k0, k1, 0u, idx, &o0, &o1);
  return bits_to_normal(o0 ^ o1);
}

__device__ __forceinline__ ushort f2bf(float f){
  return __builtin_bit_cast(ushort, __float2bfloat16(f));
}
__device__ __forceinline__ float bf2f(ushort u){ return __uint_as_float(((uint32_t)u) << 16); }

// 8 bf16 normals (counters base..base+7) into a uint4 (registers)
__device__ __forceinline__ void gen8(uint32_t k0, uint32_t k1, uint32_t base, uint4* g){
  union { ushort u[8]; uint4 q; } pk;
  #pragma unroll
  for (int j = 0; j < 8; ++j) pk.u[j] = f2bf(rng_normal(k0,k1,base+(uint32_t)j));
  *g = pk.q;
}

// ---------------- fused prepA + prepB ----------------
__global__ void k_prepAB(const float* __restrict__ saWo, const float* __restrict__ saWqkv,
                         const float* __restrict__ caWo, const float* __restrict__ caWqkv,
                         const float* __restrict__ sabqkv, const float* __restrict__ sabo,
                         const float* __restrict__ cabqkv, const float* __restrict__ cabo,
                         const float* __restrict__ W2, const float* __restrict__ pb2,
                         float* __restrict__ S, float* __restrict__ U,
                         float* __restrict__ s0, float* __restrict__ u0, float* __restrict__ cb,
                         uint32_t* __restrict__ dkeys){
  int blk = blockIdx.x, tid = threadIdx.x;
  if (blk < 512){
    int idx = (blk & 255) * 64 + tid;
    int i = idx >> 7, j = idx & 127;
    if (blk < 256){
      float acc = (i == j) ? 1.0f : 0.0f;
      for (int k = 0; k < H_; ++k) acc += saWo[i*H_ + k] * saWqkv[(2*H_ + k)*H_ + j];
      S[idx] = acc;
    } else {
      float acc = 0.0f;
      for (int k = 0; k < H_; ++k) acc += caWo[i*H_ + k] * caWqkv[(2*H_ + k)*H_ + j];
      U[idx] = acc;
    }
  } else {
    int b2 = blk - 512;
    if (b2 == 0 && tid == 0){
      for (uint32_t i = 0; i < 11; ++i){
        uint32_t a, b; tf2x32(0u, 42u, 0u, i, &a, &b);
        dkeys[2*i] = a; dkeys[2*i+1] = b;
      }
    }
    if (b2 < 2){
      int i = b2*64 + tid;
      float acc = sabo[i];
      for (int k = 0; k < H_; ++k) acc += saWo[i*H_ + k] * sabqkv[2*H_ + k];
      s0[i] = acc;
    } else if (b2 < 4){
      int i = (b2-2)*64 + tid;
      float acc = cabo[i];
      for (int k = 0; k < H_; ++k) acc += caWo[i*H_ + k] * cabqkv[2*H_ + k];
      u0[i] = acc;
    } else {
      int j = (b2-4)*64 + tid;
      float acc = 0.0f;
      for (int c = 0; c < XD_; ++c) acc += pb2[c] * W2[(size_t)c*H_ + j];
      cb[j] = acc;
    }
  }
}

__global__ void k_prepTR(const float* __restrict__ S, const float* __restrict__ U,
                         const float* __restrict__ xpW, const float* __restrict__ zpW,
                         const float* __restrict__ xpb, const float* __restrict__ zpb,
                         const float* __restrict__ s0, const float* __restrict__ u0,
                         float* __restrict__ T, float* __restrict__ R,
                         float* __restrict__ t0, float* __restrict__ r0v){
  int blk = blockIdx.x, tid = threadIdx.x;
  if (blk < 128){
    int idx = blk*64 + tid;
    int i = idx >> 6, e = idx & 63;
    float acc = 0.0f;
    for (int m = 0; m < H_; ++m) acc += S[i*H_ + m] * xpW[m*XE_ + e];
    T[idx] = acc;
  } else if (blk < 2176){
    int idx = (blk-128)*64 + tid;
    int i = idx >> 10, k = idx & 1023;
    float acc = 0.0f;
    for (int m = 0; m < H_; ++m) acc += U[i*H_ + m] * zpW[(size_t)m*ZD_ + k];
    R[idx] = acc;
  } else if (blk < 2178){
    int i = (blk-2176)*64 + tid;
    float acc = s0[i];
    for (int m = 0; m < H_; ++m) acc += S[i*H_ + m] * xpb[m];
    t0[i] = acc;
  } else {
    int i = (blk-2178)*64 + tid;
    float acc = u0[i];
    for (int m = 0; m < H_; ++m) acc += U[i*H_ + m] * zpb[m];
    r0v[i] = acc;
  }
}

// ---------------- fused prepWXT + prepMG_part ----------------
__global__ void k_prepWM(const float* __restrict__ W2, const float* __restrict__ T,
                         const float* __restrict__ embW, const float* __restrict__ embb,
                         const float* __restrict__ t0, const float* __restrict__ W1,
                         const float* __restrict__ R,
                         ushort* __restrict__ WXT, float* __restrict__ q0,
                         float* __restrict__ Mpart, float* __restrict__ Gpart){
  if (blockIdx.x < 4096){
    int idx = blockIdx.x*256 + threadIdx.x;   // 1048576
    int j = idx >> 12, c = idx & 4095;
    float v;
    if (j < H_) v = W2[(size_t)c*H_ + j];
    else {
      int i = j - H_;
      float acc = 0.0f;
      for (int e = 0; e < XE_; ++e) acc += T[i*XE_ + e] * embW[(size_t)e*XD_ + c];
      v = acc;
    }
    WXT[idx] = f2bf(v);
    if (idx < H_){
      float acc = t0[idx];
      for (int e = 0; e < XE_; ++e) acc += T[idx*XE_ + e] * embb[e];
      q0[idx] = acc;
    }
  } else {
    int gid = (blockIdx.x - 4096)*256 + threadIdx.x;   // 393216
    if (gid < 131072){
      int slice = gid >> 14, i = gid & 16383;
      int j1 = i >> 7, j2 = i & 127;
      int c0 = slice*512;
      float acc = 0.0f;
      for (int c = c0; c < c0+512; ++c)
        acc += W2[(size_t)c*H_ + j1] * W2[(size_t)c*H_ + j2];
      Mpart[(size_t)slice*16384 + i] = acc;
    } else {
      int g = gid - 131072;
      int slice = g >> 15, i2 = g & 32767;
      int i = i2 >> 7, k = i2 & 127;
      int m0 = slice*128;
      float acc = 0.0f;
      if (i < 128){
        for (int m = m0; m < m0+128; ++m)
          acc += W1[(size_t)i*ZD_ + m] * W1[(size_t)k*ZD_ + m];
      } else {
        for (int m = m0; m < m0+128; ++m)
          acc += W1[(size_t)k*ZD_ + m] * R[(size_t)(i-128)*ZD_ + m];
      }
      Gpart[(size_t)slice*32768 + i2] = acc;
    }
  }
}

// W2bf; Mbf=f2bf(2*sum Mpart); FBTswz fragment-ordered; GGr=f2bf(-0.005*sum Gpart)
__global__ void k_conv(const float* __restrict__ W2, const float* __restrict__ W1,
                       const float* __restrict__ R,
                       const float* __restrict__ Mpart, const float* __restrict__ Gpart,
                       ushort* __restrict__ W2bf, ushort* __restrict__ Mbf,
                       ushort* __restrict__ FBT, ushort* __restrict__ GGr){
  int idx = blockIdx.x*256 + threadIdx.x;   // 835584
  if (idx < 524288) W2bf[idx] = f2bf(W2[idx]);
  else if (idx < 540672){
    int i = idx - 524288;
    float s = 0.0f;
    #pragma unroll
    for (int p = 0; p < 8; ++p) s += Mpart[(size_t)p*16384 + i];
    Mbf[i] = f2bf(2.0f*s);
  } else if (idx < 802816){
    int i = idx - 540672;                 // swizzled dest index
    int j    = i & 7;
    int lane = (i >> 3) & 63;
    int hh   = (i >> 9) & 1;
    int itt  = (i >> 10) & 15;
    int cf   = i >> 14;
    int srow = cf*16 + (lane & 15);
    int scol = itt*64 + hh*32 + ((lane >> 4) << 3) + j;
    float v = (srow < H_) ? W1[(size_t)srow*ZD_ + scol] : R[(size_t)(srow-H_)*ZD_ + scol];
    FBT[i] = f2bf(v);
  } else {
    int i = idx - 802816;
    float s = 0.0f;
    #pragma unroll
    for (int p = 0; p < 8; ++p) s += Gpart[(size_t)p*32768 + i];
    GGr[i] = f2bf(-0.005f*s);
  }
}

// ---------------- fused noiseproj + xpass (heterogeneous blocks) ----------------
// R14: noiseproj hit VALU 87.6% (near the ~274us RNG issue floor) but runs SERIAL
// with the memory/MFMA-bound xpass. Fusion retry (R10 failed because the THEN
// noiseproj was LDS-pipelined at broken occupancy; today's is reg-only — adding
// xpass's 46KB LDS reservation leaves its 2-blk/CU VGPR-limited occupancy intact).
// 15-block groups: 11 noiseproj + 4 xpass (1408 + 512 = 1920).
__global__ __launch_bounds__(256) void k_npx2(
    const ushort* __restrict__ FBT, const uint32_t* __restrict__ dkeys,
    float* __restrict__ y0c0, ushort* __restrict__ NWR,
    const float* __restrict__ x, const ushort* __restrict__ WXT,
    const float* __restrict__ cb, const float* __restrict__ q0v,
    float* __restrict__ cneg, float* __restrict__ h1pre){
  __shared__ __align__(16) ushort smem[23040];   // 46080 B (xpass branch only)
  const int t = threadIdx.x, lane = t & 63, w = t >> 6;
  const int l15 = lane & 15, rq = (lane >> 4)*4, kq8 = (lane >> 4)*8;
  const int grp = blockIdx.x / 15, rem = blockIdx.x % 15;

  if (rem < 11){
    // ======== noiseproj: pass p rows [8192][1024] RNG @ FBTswz -> [8192][256]
    const int gwid = (grp*11 + rem)*4 + w;     // 0..5631
    const int p = gwid >> 9, mb = gwid & 511;
    const int row0 = mb*16;
    const uint32_t k0 = dkeys[2*p], k1 = dkeys[2*p+1];
    const uint32_t rbase = (uint32_t)(row0 + l15)*1024u + (uint32_t)((lane >> 4)*8);
    f32x4_t acc[16] = {};
    #pragma unroll 1
    for (int it = 0; it < 16; ++it){
      uint4 br[16];
      {
        const ushort* fb = FBT + (size_t)(it*2)*512 + lane*8;
        #pragma unroll
        for (int cf = 0; cf < 16; ++cf) br[cf] = *(const uint4*)(fb + (size_t)cf*16384);
      }
      __builtin_amdgcn_sched_barrier(0);
      uint4 g0; gen8(k0, k1, rbase + (uint32_t)(it*64), &g0);
      short8_t a0 = __builtin_bit_cast(short8_t, g0);
      #pragma unroll
      for (int cf = 0; cf < 16; ++cf)
        acc[cf] = MFMA16(a0, __builtin_bit_cast(short8_t, br[cf]), acc[cf]);
      {
        const ushort* fb = FBT + (size_t)(it*2+1)*512 + lane*8;
        #pragma unroll
        for (int cf = 0; cf < 16; ++cf) br[cf] = *(const uint4*)(fb + (size_t)cf*16384);
      }
      __builtin_amdgcn_sched_barrier(0);
      uint4 g1; gen8(k0, k1, rbase + (uint32_t)(it*64 + 32), &g1);
      short8_t a1 = __builtin_bit_cast(short8_t, g1);
      #pragma unroll
      for (int cf = 0; cf < 16; ++cf)
        acc[cf] = MFMA16(a1, __builtin_bit_cast(short8_t, br[cf]), acc[cf]);
    }
    #pragma unroll
    for (int cf = 0; cf < 16; ++cf){
      int col = cf*16 + l15;
      #pragma unroll
      for (int r = 0; r < 4; ++r){
        int row = row0 + rq + r;
        float v = acc[cf][r];
        if (p == 0) y0c0[(size_t)row*256 + col] = v;
        else NWR[(size_t)(p-1)*2097152 + (size_t)row*256 + col] = f2bf(0.1f*v);
      }
    }
  } else {
    // ======== xpass: [cneg | h1pre] = x @ WXT^T  (BM=32, BN=128)
    ushort* xt0 = smem;            // 32*72
    ushort* xt1 = smem + 2304;
    ushort* bt0 = smem + 4608;     // 128*72
    ushort* bt1 = smem + 13824;
    const int xp = grp*4 + (rem - 11);   // 0..511
    const int bm = xp >> 1, bn = xp & 1;
    const int row0 = bm*32, ncol0 = bn*128;
    const int rt = w & 1, cb4 = (w >> 1)*4;
    const int xr = t >> 3, xk = (t & 7)*8;
    const int wn = t >> 1, wk = (t & 1)*32;
    f32x4_t acc[4] = {};
    {
      float4 v0 = *(const float4*)&x[(size_t)(row0+xr)*XD_ + xk];
      float4 v1 = *(const float4*)&x[(size_t)(row0+xr)*XD_ + xk + 4];
      union { ushort u[8]; uint4 q; } p;
      p.u[0]=f2bf(v0.x); p.u[1]=f2bf(v0.y); p.u[2]=f2bf(v0.z); p.u[3]=f2bf(v0.w);
      p.u[4]=f2bf(v1.x); p.u[5]=f2bf(v1.y); p.u[6]=f2bf(v1.z); p.u[7]=f2bf(v1.w);
      *(uint4*)&xt0[xr*72 + xk] = p.q;
      const ushort* s = &WXT[(size_t)(ncol0+wn)*XD_ + wk];
      uint4 b0v=*(const uint4*)s, b1v=*(const uint4*)(s+8), b2v=*(const uint4*)(s+16), b3v=*(const uint4*)(s+24);
      ushort* d = &bt0[wn*72 + wk];
      *(uint4*)d=b0v; *(uint4*)(d+8)=b1v; *(uint4*)(d+16)=b2v; *(uint4*)(d+24)=b3v;
    }
    float4 xv0, xv1; uint4 wb0, wb1, wb2, wb3;
    {
      xv0 = *(const float4*)&x[(size_t)(row0+xr)*XD_ + 64 + xk];
      xv1 = *(const float4*)&x[(size_t)(row0+xr)*XD_ + 64 + xk + 4];
      const ushort* s = &WXT[(size_t)(ncol0+wn)*XD_ + 64 + wk];
      wb0=*(const uint4*)s; wb1=*(const uint4*)(s+8); wb2=*(const uint4*)(s+16); wb3=*(const uint4*)(s+24);
    }
    #pragma unroll 1
    for (int it = 0; it < 64; ++it){
      __syncthreads();
      if (it < 63){
        union { ushort u[8]; uint4 q; } p;
        p.u[0]=f2bf(xv0.x); p.u[1]=f2bf(xv0.y); p.u[2]=f2bf(xv0.z); p.u[3]=f2bf(xv0.w);
        p.u[4]=f2bf(xv1.x); p.u[5]=f2bf(xv1.y); p.u[6]=f2bf(xv1.z); p.u[7]=f2bf(xv1.w);
        *(uint4*)&(((it+1)&1) ? xt1 : xt0)[xr*72 + xk] = p.q;
        ushort* d = &(((it+1)&1) ? bt1 : bt0)[wn*72 + wk];
        *(uint4*)d=wb0; *(uint4*)(d+8)=wb1; *(uint4*)(d+16)=wb2; *(uint4*)(d+24)=wb3;
      }
      if (it < 62){
        const int kt = (it+2)*64;
        xv0 = *(const float4*)&x[(size_t)(row0+xr)*XD_ + kt + xk];
        xv1 = *(const float4*)&x[(size_t)(row0+xr)*XD_ + kt + xk + 4];
        const ushort* s = &WXT[(size_t)(ncol0+wn)*XD_ + kt + wk];
        wb0=*(const uint4*)s; wb1=*(const uint4*)(s+8); wb2=*(const uint4*)(s+16); wb3=*(const uint4*)(s+24);
      }
      const ushort* xb = &((it&1) ? xt1 : xt0)[(rt*16+l15)*72];
      const ushort* bb = (it&1) ? bt1 : bt0;
      #pragma unroll
      for (int h = 0; h < 2; ++h){
        short8_t a = *(const short8_t*)(xb + h*32 + kq8);
        #pragma unroll
        for (int c = 0; c < 4; ++c){
          short8_t b = *(const short8_t*)(bb + ((cb4+c)*16+l15)*72 + h*32 + kq8);
          acc[c] = MFMA16(a, b, acc[c]);
        }
      }
    }
    #pragma unroll
    for (int c = 0; c < 4; ++c){
      int jl = (cb4+c)*16 + l15;
      #pragma unroll
      for (int r = 0; r < 4; ++r){
        int row = row0 + rt*16 + rq + r;
        float v = acc[c][r];
        if (bn == 0) cneg[(size_t)row*H_ + jl] = 2.0f*(cb[jl] - v);
        else         h1pre[(size_t)row*H_ + jl] = v + q0v[jl];
      }
    }
  }
}

// ---------------- wave reduction ----------------
__device__ __forceinline__ float wsum64(float v){
  #pragma unroll
  for (int off = 32; off > 0; off >>= 1) v += __shfl_xor(v, off, 64);
  return v;
}

// ---------------- 128-dim Langevin + fused transformer tail ----------------
// lv2's waves 4-7 hold capre in accumulators — route via LDS, then 8 waves x 2 rows
// run the LN/FFN/LN tail per-wave (wave-local row buffers, no extra barriers).
// Kills the k_tail launch and the 8.4MB capre global round-trip.
__global__ __launch_bounds__(512) void k_lv2t(
    const ushort* __restrict__ M2bf, const ushort* __restrict__ GGr,
    const float* __restrict__ y0c0, const ushort* __restrict__ NWR,
    const float* __restrict__ b1, const float* __restrict__ r0v,
    const float* __restrict__ cneg, const float* __restrict__ h1pre,
    const float* __restrict__ ln1g, const float* __restrict__ ln1b,
    const float* __restrict__ ln2g, const float* __restrict__ ln2b,
    const float* __restrict__ ln3g, const float* __restrict__ ln3b,
    const float* __restrict__ fW1, const float* __restrict__ fb1,
    const float* __restrict__ fW2, const float* __restrict__ fb2,
    const float* __restrict__ outW, const float* __restrict__ outb,
    ushort* __restrict__ hfin_bf, float* __restrict__ ypred){
  __shared__ __align__(16) ushort abuf[16*136];
  __shared__ __align__(16) ushort glbuf[16*136];
  __shared__ __align__(16) float caplds[16][132];
  __shared__ __align__(16) float rowA[8][132];
  __shared__ __align__(16) float rowB[8][132];
  const int t = threadIdx.x, lane = t & 63, w = t >> 6;
  const int l15 = lane & 15, kq8 = (lane >> 4)*8, rq = (lane >> 4)*4;
  const int b0 = blockIdx.x * 16;
  const int myc = w*16 + l15;
  const int col2 = w*32 + l15;

  f32x4_t acc[2];
  #pragma unroll
  for (int nf = 0; nf < 2; ++nf)
    #pragma unroll
    for (int r = 0; r < 4; ++r)
      acc[nf][r] = y0c0[(size_t)(b0+rq+r)*256 + col2 + nf*16];
  float cn[4];
  #pragma unroll
  for (int r = 0; r < 4; ++r) cn[r] = cneg[(size_t)(b0+rq+r)*H_ + myc];
  float bb2[2];
  bb2[0] = (w < 4) ? b1[col2] : 0.0f;
  bb2[1] = (w < 4) ? b1[col2+16] : 0.0f;
  ushort nx[8];
  #pragma unroll
  for (int nf = 0; nf < 2; ++nf)
    #pragma unroll
    for (int r = 0; r < 4; ++r)
      nx[nf*4+r] = NWR[(size_t)(b0+rq+r)*256 + col2 + nf*16];

  #pragma unroll 1
  for (int s = 0; s < 10; ++s){
    if (w < 4){
      #pragma unroll
      for (int nf = 0; nf < 2; ++nf)
        #pragma unroll
        for (int r = 0; r < 4; ++r)
          abuf[(rq+r)*136 + col2 + nf*16] = f2bf(fmaxf(acc[nf][r] + bb2[nf], 0.0f));
    }
    __syncthreads();
    f32x4_t g2 = {};
    #pragma unroll
    for (int h = 0; h < 4; ++h){
      short8_t a = *(const short8_t*)&abuf[l15*136 + h*32 + kq8];
      short8_t b = *(const short8_t*)&M2bf[(size_t)myc*H_ + h*32 + kq8];
      g2 = MFMA16(a, b, g2);
    }
    #pragma unroll
    for (int r = 0; r < 4; ++r){
      float g = (abuf[(rq+r)*136 + myc] != 0) ? (g2[r] + cn[r]) : 0.0f;
      glbuf[(rq+r)*136 + myc] = f2bf(g);
    }
    __syncthreads();
    #pragma unroll
    for (int nf = 0; nf < 2; ++nf)
      #pragma unroll
      for (int h = 0; h < 4; ++h){
        short8_t a = *(const short8_t*)&glbuf[l15*136 + h*32 + kq8];
        short8_t b = *(const short8_t*)&GGr[(size_t)(col2 + nf*16)*H_ + h*32 + kq8];
        acc[nf] = MFMA16(a, b, acc[nf]);
      }
    #pragma unroll
    for (int nf = 0; nf < 2; ++nf)
      #pragma unroll
      for (int r = 0; r < 4; ++r)
        acc[nf][r] += bf2f(nx[nf*4+r]);
    if (s < 9){
      #pragma unroll
      for (int nf = 0; nf < 2; ++nf)
        #pragma unroll
        for (int r = 0; r < 4; ++r)
          nx[nf*4+r] = NWR[(size_t)(s+1)*2097152 + (size_t)(b0+rq+r)*256 + col2 + nf*16];
    }
    __syncthreads();
  }
  if (w < 4){
    #pragma unroll
    for (int nf = 0; nf < 2; ++nf)
      #pragma unroll
      for (int r = 0; r < 4; ++r)
        hfin_bf[(size_t)(b0+rq+r)*H_ + col2 + nf*16] = f2bf(fmaxf(acc[nf][r] + bb2[nf], 0.0f));
  } else {
    #pragma unroll
    for (int nf = 0; nf < 2; ++nf)
      #pragma unroll
      for (int r = 0; r < 4; ++r)
        caplds[rq+r][col2 + nf*16 - 128] = acc[nf][r] + r0v[col2 + nf*16 - 128];
  }
  __syncthreads();

  // -------- fused tail: wave w handles rows 2w, 2w+1
  const int l = lane;
  #pragma unroll 1
  for (int j = 0; j < 2; ++j){
    const int rloc = w*2 + j;
    const int rr = b0 + rloc;
    const float* hp = h1pre + (size_t)rr * H_;
    float x0 = hp[l], x1 = hp[l+64];
    float m = wsum64(x0 + x1) * (1.0f/128.0f);
    float d0 = x0 - m, d1 = x1 - m;
    float v = wsum64(d0*d0 + d1*d1) * (1.0f/128.0f);
    float rs = rsqrtf(v + 1e-5f);
    float h1a = d0 * rs * ln1g[l]    + ln1b[l];
    float h1b = d1 * rs * ln1g[l+64] + ln1b[l+64];
    x0 = h1a + caplds[rloc][l]; x1 = h1b + caplds[rloc][l+64];
    m = wsum64(x0 + x1) * (1.0f/128.0f);
    d0 = x0 - m; d1 = x1 - m;
    v = wsum64(d0*d0 + d1*d1) * (1.0f/128.0f);
    rs = rsqrtf(v + 1e-5f);
    float h2a = d0 * rs * ln2g[l]    + ln2b[l];
    float h2b = d1 * rs * ln2g[l+64] + ln2b[l+64];
    rowA[w][l] = h2a; rowA[w][l+64] = h2b;
    float ta = fb1[l], tb = fb1[l+64];
    #pragma unroll 8
    for (int m4 = 0; m4 < H_; m4 += 4){
      float4 hv = *(const float4*)&rowA[w][m4];
      float4 wa = *(const float4*)&fW1[(size_t)l*H_ + m4];
      float4 wb = *(const float4*)&fW1[(size_t)(l+64)*H_ + m4];
      ta = fmaf(wa.x, hv.x, ta); ta = fmaf(wa.y, hv.y, ta); ta = fmaf(wa.z, hv.z, ta); ta = fmaf(wa.w, hv.w, ta);
      tb = fmaf(wb.x, hv.x, tb); tb = fmaf(wb.y, hv.y, tb); tb = fmaf(wb.z, hv.z, tb); tb = fmaf(wb.w, hv.w, tb);
    }
    ta = fmaxf(ta, 0.0f); tb = fmaxf(tb, 0.0f);
    rowB[w][l] = ta; rowB[w][l+64] = tb;
    float fa = fb2[l], fbv = fb2[l+64];
    #pragma unroll 8
    for (int m4 = 0; m4 < H_; m4 += 4){
      float4 tv = *(const float4*)&rowB[w][m4];
      float4 wa = *(const float4*)&fW2[(size_t)l*H_ + m4];
      float4 wb = *(const float4*)&fW2[(size_t)(l+64)*H_ + m4];
      fa  = fmaf(wa.x, tv.x, fa);  fa  = fmaf(wa.y, tv.y, fa);  fa  = fmaf(wa.z, tv.z, fa);  fa  = fmaf(wa.w, tv.w, fa);
      fbv = fmaf(wb.x, tv.x, fbv); fbv = fmaf(wb.y, tv.y, fbv); fbv = fmaf(wb.z, tv.z, fbv); fbv = fmaf(wb.w, tv.w, fbv);
    }
    x0 = h2a + fa; x1 = h2b + fbv;
    m = wsum64(x0 + x1) * (1.0f/128.0f);
    d0 = x0 - m; d1 = x1 - m;
    v = wsum64(d0*d0 + d1*d1) * (1.0f/128.0f);
    rs = rsqrtf(v + 1e-5f);
    float h3a = d0 * rs * ln3g[l]    + ln3b[l];
    float h3b = d1 * rs * ln3g[l+64] + ln3b[l+64];
    float py = wsum64(outW[l]*h3a + outW[l+64]*h3b);
    if (l == 0) ypred[rr] = py + outb[0];
  }
}

// ---------------- x_recon (MFMA): out = hfin @ W2^T + b2 ----------------
__global__ __launch_bounds__(256) void k_xrecon_mfma(
    const ushort* __restrict__ hfin_bf, const ushort* __restrict__ W2bf,
    const float* __restrict__ b2, float* __restrict__ out){
  __shared__ __align__(16) ushort at[64*136];
  __shared__ __align__(16) ushort bt[128*136];
  const int tid = threadIdx.x, lane = tid & 63, w = tid >> 6;
  const int bm = blockIdx.x >> 5, bn = blockIdx.x & 31;
  const int row0 = bm*64, c0 = bn*128;
  const int l15 = lane & 15, kq8 = (lane >> 4)*8, rq = (lane >> 4)*4;
  { int r = tid >> 2, kq = (tid & 3)*32;
    const ushort* src = &hfin_bf[(size_t)(row0 + r)*H_ + kq];
    #pragma unroll
    for (int i = 0; i < 4; ++i) *(uint4*)&at[r*136 + kq + 8*i] = *(const uint4*)(src + 8*i);
  }
  { int n = tid >> 1, kh = (tid & 1)*64;
    const ushort* src = &W2bf[(size_t)(c0 + n)*H_ + kh];
    #pragma unroll
    for (int i = 0; i < 8; ++i) *(uint4*)&bt[n*136 + kh + 8*i] = *(const uint4*)(src + 8*i);
  }
  __syncthreads();
  f32x4_t acc[8] = {};
  #pragma unroll
  for (int k = 0; k < 4; ++k){
    short8_t a = *(const short8_t*)&at[(w*16 + l15)*136 + k*32 + kq8];
    #pragma unroll
    for (int nf = 0; nf < 8; ++nf){
      short8_t b = *(const short8_t*)&bt[(nf*16 + l15)*136 + k*32 + kq8];
      acc[nf] = MFMA16(a, b, acc[nf]);
    }
  }
  #pragma unroll
  for (int nf = 0; nf < 8; ++nf){
    int c = c0 + nf*16 + l15;
    float bbv = b2[c];
    #pragma unroll
    for (int r = 0; r < 4; ++r){
      int row = row0 + w*16 + rq + r;
      out[(size_t)row*XD_ + c] = acc[nf][r] + bbv;
    }
  }
}

// ---------------- host ----------------
extern "C" void kernel_launch(void* const* d_in, const int* in_sizes, int n_in,
                              void* d_out, int out_size, void* d_ws, size_t ws_size,
                              hipStream_t stream){
  const float* x      = (const float*)d_in[0];
  const float* pxW1   = (const float*)d_in[1];
  const float* pxb1   = (const float*)d_in[2];
  const float* pxW2   = (const float*)d_in[3];
  const float* pxb2   = (const float*)d_in[4];
  const float* embW   = (const float*)d_in[5];
  const float* embb   = (const float*)d_in[6];
  const float* xpW    = (const float*)d_in[7];
  const float* xpb    = (const float*)d_in[8];
  const float* zpW    = (const float*)d_in[9];
  const float* zpb    = (const float*)d_in[10];
  const float* saWqkv = (const float*)d_in[11];
  const float* sabqkv = (const float*)d_in[12];
  const float* saWo   = (const float*)d_in[13];
  const float* sabo   = (const float*)d_in[14];
  const float* caWqkv = (const float*)d_in[15];
  const float* cabqkv = (const float*)d_in[16];
  const float* caWo   = (const float*)d_in[17];
  const float* cabo   = (const float*)d_in[18];
  const float* fW1    = (const float*)d_in[19];
  const float* fb1    = (const float*)d_in[20];
  const float* fW2    = (const float*)d_in[21];
  const float* fb2    = (const float*)d_in[22];
  const float* ln1g   = (const float*)d_in[23];
  const float* ln1b   = (const float*)d_in[24];
  const float* ln2g   = (const float*)d_in[25];
  const float* ln2b   = (const float*)d_in[26];
  const float* ln3g   = (const float*)d_in[27];
  const float* ln3b   = (const float*)d_in[28];
  const float* outW   = (const float*)d_in[29];
  const float* outb   = (const float*)d_in[30];
  (void)in_sizes; (void)n_in; (void)out_size; (void)ws_size;

  float* ws    = (float*)d_ws;
  float* cneg  = ws;                          // 1048576
  float* h1pre = cneg + (size_t)B_*H_;        // 1048576
  float* Rm    = h1pre + (size_t)B_*H_;       // 131072
  float* Sm    = Rm + (size_t)H_*ZD_;         // 16384
  float* Um    = Sm + H_*H_;                  // 16384
  float* Tm    = Um + H_*H_;                  // 8192
  float* vs0   = Tm + H_*XE_;
  float* vu0   = vs0 + H_;
  float* vt0   = vu0 + H_;
  float* vq0   = vt0 + H_;
  float* vr0   = vq0 + H_;
  float* vcb   = vr0 + H_;
  float* Mpart = vcb + H_;                    // 131072
  float* Gpart = Mpart + 131072;              // 262144
  uint32_t* dkeys = (uint32_t*)(Gpart + 262144);  // 32 u32
  float* y0c0  = (float*)(dkeys + 32);        // 2097152 f32
  ushort* WXT   = (ushort*)(y0c0 + (size_t)B_*256);  // 1048576
  ushort* W2bf  = WXT + (size_t)256*XD_;      // 524288
  ushort* Mbf   = W2bf + (size_t)XD_*H_;      // 16384 (=2M)
  ushort* FBT   = Mbf + H_*H_;                // 262144 (fragment-ordered swz)
  ushort* GGr   = FBT + (size_t)256*ZD_;      // 32768
  ushort* hfin  = GGr + (size_t)256*H_;       // 1048576
  ushort* NWR   = hfin + (size_t)B_*H_;       // 20971520 (10 x 8192 x 256)

  float* xre   = (float*)d_out;
  float* ypred = xre + (size_t)B_*XD_;

  k_prepAB  <<<518,  64, 0, stream>>>(saWo, saWqkv, caWo, caWqkv, sabqkv, sabo,
                                      cabqkv, cabo, pxW2, pxb2, Sm, Um, vs0, vu0, vcb, dkeys);
  k_prepTR  <<<2180, 64, 0, stream>>>(Sm, Um, xpW, zpW, xpb, zpb, vs0, vu0, Tm, Rm, vt0, vr0);
  k_prepWM  <<<5632, 256, 0, stream>>>(pxW2, Tm, embW, embb, vt0, pxW1, Rm,
                                       WXT, vq0, Mpart, Gpart);
  k_conv    <<<3264, 256, 0, stream>>>(pxW2, pxW1, Rm, Mpart, Gpart, W2bf, Mbf, FBT, GGr);
  k_npx2    <<<1920, 256, 0, stream>>>(FBT, dkeys, y0c0, NWR, x, WXT, vcb, vq0, cneg, h1pre);
  k_lv2t    <<<512, 512, 0, stream>>>(Mbf, GGr, y0c0, NWR, pxb1, vr0, cneg, h1pre,
                                      ln1g, ln1b, ln2g, ln2b, ln3g, ln3b,
                                      fW1, fb1, fW2, fb2, outW, outb, hfin, ypred);
  k_xrecon_mfma <<<4096, 256, 0, stream>>>(hfin, W2bf, pxb2, xre);
}